// Round 5
// baseline (2209.521 us; speedup 1.0000x reference)
//
#include <hip/hip_runtime.h>

namespace {
constexpr int N  = 500000;
constexpr int E  = 3000000;
constexpr int C  = 128;
constexpr int M  = 125000;
constexpr int NP = 5;
constexpr int NB = 131072;      // key buckets = top-17 bits of biased int32 key

// d_out flat layout (float32), reference return order:
constexpr long long O_XF  = 0;          // new_xfinal      M*C
constexpr long long O_NEI = 16000000;   // new_edge_index  2*E
constexpr long long O_POS = 22000000;   // new_pos         M*2
constexpr long long O_IAT = 22250000;   // indexatttennew  M*5
constexpr long long O_NB  = 22875000;   // new_batch       M
constexpr long long O_EIP = 23000000;   // edge_index      2*E
constexpr long long O_CL  = 29000000;   // cluster         N
constexpr long long O_BAT = 29500000;   // batch           N

// scratch inside d_out, region [O_EIP, O_EIP+E) — only k_pass (last kernel)
// writes there; all scratch users finish first.
constexpr long long S_CNT = 23000000;   // counts   M floats
constexpr long long S_CLU = 23200000;   // cluster  N ints
constexpr long long S_BCN = 23800000;   // bcnt     NB ints
constexpr long long S_BOF = 24000000;   // boff     NB+1 ints
constexpr long long S_UCN = 24200000;   // ucount   NB ints
constexpr long long S_UOF = 24400000;   // uoff     NB+1 ints
// bdata (E uints, biased keys) in [O_EIP+E, O_EIP+2E) = row 1 of passthrough.
}

// mode: 1=int64, 3=float64, 0=int32, 2=float32
__global__ void k_detect(const void* __restrict__ ei, int* __restrict__ flag) {
    if (threadIdx.x != 0 || blockIdx.x != 0) return;
    const unsigned long long* q = (const unsigned long long*)ei;
    unsigned long long hi = 0, lo = 0;
    for (int i = 0; i < 64; ++i) {
        unsigned long long a = q[i];
        unsigned long long b = q[(size_t)E / 2 + i];
        hi |= (a >> 32) | (b >> 32);
        lo |= (a & 0xffffffffULL) | (b & 0xffffffffULL);
    }
    int mode;
    if (hi == 0) mode = 1;
    else if (lo == 0) mode = 3;
    else {
        const int* p = (const int*)ei;
        int ok = 1;
        for (int i = 0; i < 256; ++i) {
            int v0 = p[i], v1 = p[E + i];
            if (v0 < 0 || v0 >= N || v1 < 0 || v1 >= N) ok = 0;
        }
        mode = ok ? 0 : 2;
    }
    *flag = mode;
}

__device__ __forceinline__ int load_ei(const void* ei, long long idx, int mode) {
    long long v;
    if (mode == 1)      v = ((const long long*)ei)[idx];
    else if (mode == 0) v = (long long)((const int*)ei)[idx];
    else if (mode == 3) v = (long long)(((const double*)ei)[idx]);
    else                v = (long long)(((const float*)ei)[idx]);
    if (v < 0 || v >= N) v = 0;
    return (int)v;
}

// int32-wraparound key (JAX default x64-disabled semantics), biased for
// unsigned compare == signed compare.
__device__ __forceinline__ unsigned make_key(int c0, int c1) {
    unsigned uv = (unsigned)c0 * (unsigned)M + (unsigned)c1;   // natural mod 2^32
    return uv ^ 0x80000000u;
}

__global__ void k_rows(const float* __restrict__ iat, const float* __restrict__ batch,
                       const float* __restrict__ xpos, const int* __restrict__ pool,
                       float* __restrict__ out) {
    int i = blockIdx.x * blockDim.x + threadIdx.x;
    if (i >= N) return;
    int p = pool[0];
    int c = (int)iat[(long long)i * NP + p];
    ((int*)(out + S_CLU))[i] = c;
    out[O_CL + i] = (float)c;
    float b = batch[i];
    out[O_BAT + i] = b;
    atomicAdd(out + S_CNT + c, 1.0f);
    atomicAdd(&out[O_POS + (long long)c * 2 + 0], xpos[(long long)i * 2 + 0]);
    atomicAdd(&out[O_POS + (long long)c * 2 + 1], xpos[(long long)i * 2 + 1]);
#pragma unroll
    for (int j = 0; j < NP; ++j)
        atomicAdd(&out[O_IAT + (long long)c * NP + j], iat[(long long)i * NP + j]);
    atomicAdd(&out[O_NB + c], b);
}

__global__ void k_xsum(const float4* __restrict__ x4, float* __restrict__ out) {
    long long t = (long long)blockIdx.x * blockDim.x + threadIdx.x;
    if (t >= (long long)N * 32) return;
    int i = (int)(t >> 5);
    int g = (int)(t & 31);
    float4 v = x4[(long long)i * 32 + g];
    int c = ((const int*)(out + S_CLU))[i];
    float* dst = out + O_XF + (long long)c * C + g * 4;
    atomicAdd(dst + 0, v.x);
    atomicAdd(dst + 1, v.y);
    atomicAdd(dst + 2, v.z);
    atomicAdd(dst + 3, v.w);
}

__global__ void k_final(float* __restrict__ out) {
    long long t = (long long)blockIdx.x * blockDim.x + threadIdx.x;
    if (t >= (long long)M * 136) return;
    int m = (int)(t / 136);
    int j = (int)(t % 136);
    float cnt = out[S_CNT + m];
    if (cnt < 1.0f) cnt = 1.0f;
    long long idx;
    bool tr = false;
    if (j < C)            idx = O_XF  + (long long)m * C + j;
    else if (j < C + 2)   idx = O_POS + (long long)m * 2 + (j - C);
    else if (j < C + 7) { idx = O_IAT + (long long)m * NP + (j - C - 2); tr = true; }
    else                { idx = O_NB  + m; tr = true; }
    float v = out[idx] / cnt;
    if (tr) v = truncf(v);
    out[idx] = v;
}

// histogram biased keys into NB buckets (top 17 bits)
__global__ void k_edges(const void* __restrict__ ei, const int* __restrict__ flag,
                        float* __restrict__ out) {
    int e = blockIdx.x * blockDim.x + threadIdx.x;
    if (e >= E) return;
    int mode = *flag;
    const int* cluster = (const int*)(out + S_CLU);
    int c0 = cluster[load_ei(ei, e, mode)];
    int c1 = cluster[load_ei(ei, (long long)E + e, mode)];
    unsigned key = make_key(c0, c1);
    atomicAdd((int*)(out + S_BCN) + (key >> 15), 1);
}

// single-block exclusive scan of n ints, outp has n+1 slots
__global__ void k_scan(const float* __restrict__ outbase, long long in_off,
                       long long out_off, int n) {
    const int* in = (const int*)(outbase + in_off);
    int* outp = (int*)(outbase + out_off);
    __shared__ int sh[1024];
    int tid = threadIdx.x;
    int chunk = (n + 1023) / 1024;
    int start = tid * chunk;
    int end = start + chunk;
    if (start > n) start = n;
    if (end > n) end = n;
    int s = 0;
    for (int i = start; i < end; ++i) s += in[i];
    sh[tid] = s;
    __syncthreads();
    for (int off = 1; off < 1024; off <<= 1) {
        int v = (tid >= off) ? sh[tid - off] : 0;
        __syncthreads();
        sh[tid] += v;
        __syncthreads();
    }
    int run = (tid == 0) ? 0 : sh[tid - 1];
    for (int i = start; i < end; ++i) { outp[i] = run; run += in[i]; }
    if (tid == 1023) outp[n] = sh[1023];
}

// scatter biased keys into buckets; boff becomes bucket END afterwards
__global__ void k_scatter(const void* __restrict__ ei, const int* __restrict__ flag,
                          float* __restrict__ out) {
    int e = blockIdx.x * blockDim.x + threadIdx.x;
    if (e >= E) return;
    int mode = *flag;
    const int* cluster = (const int*)(out + S_CLU);
    int c0 = cluster[load_ei(ei, e, mode)];
    int c1 = cluster[load_ei(ei, (long long)E + e, mode)];
    unsigned key = make_key(c0, c1);
    int pos = atomicAdd((int*)(out + S_BOF) + (key >> 15), 1);
    ((unsigned*)(out + O_EIP + E))[pos] = key;
}

__global__ void k_sortcnt(float* __restrict__ out) {
    int m = blockIdx.x * blockDim.x + threadIdx.x;
    if (m >= NB) return;
    const int* boff = (const int*)(out + S_BOF);
    unsigned* bdata = (unsigned*)(out + O_EIP + E);
    int start = (m == 0) ? 0 : boff[m - 1];
    int end = boff[m];
    for (int i = start + 1; i < end; ++i) {
        unsigned v = bdata[i];
        int j = i - 1;
        while (j >= start && bdata[j] > v) { bdata[j + 1] = bdata[j]; --j; }
        bdata[j + 1] = v;
    }
    int u = 0;
    unsigned prev = 0; int has = 0;
    for (int i = start; i < end; ++i) {
        unsigned v = bdata[i];
        if (!has || v != prev) { ++u; prev = v; has = 1; }
    }
    ((int*)(out + S_UCN))[m] = u;
}

// write sorted unique keys decoded as (floor-div, floor-mod) of the SIGNED
// int32 key — matches JAX x64-disabled wraparound semantics.
__global__ void k_uwrite(float* __restrict__ out) {
    int m = blockIdx.x * blockDim.x + threadIdx.x;
    if (m >= NB) return;
    const int* boff = (const int*)(out + S_BOF);
    const unsigned* bdata = (const unsigned*)(out + O_EIP + E);
    int start = (m == 0) ? 0 : boff[m - 1];
    int end = boff[m];
    long long base = ((const int*)(out + S_UOF))[m];
    unsigned prev = 0; int has = 0;
    long long j = 0;
    for (int i = start; i < end; ++i) {
        unsigned v = bdata[i];
        if (!has || v != prev) {
            long long k = (long long)(int)(v ^ 0x80000000u);   // signed key
            long long r = k % M; if (r < 0) r += M;
            long long q = (k - r) / M;
            out[O_NEI + base + j]     = (float)q;
            out[O_NEI + E + base + j] = (float)r;
            ++j;
            prev = v; has = 1;
        }
    }
}

// tail fill = last sorted unique pair (== keys.max() by construction)
__global__ void k_fill(float* __restrict__ out) {
    int p = blockIdx.x * blockDim.x + threadIdx.x;
    if (p >= E) return;
    int U = ((const int*)(out + S_UOF))[NB];
    if (p < U) return;
    float r0 = out[O_NEI + U - 1];
    float r1 = out[O_NEI + E + U - 1];
    out[O_NEI + p]     = r0;
    out[O_NEI + E + p] = r1;
}

// edge_index passthrough — LAST kernel; overwrites all scratch in [23M,29M).
__global__ void k_pass(const void* __restrict__ ei, const int* __restrict__ flag,
                       float* __restrict__ out) {
    int e = blockIdx.x * blockDim.x + threadIdx.x;
    if (e >= E) return;
    int mode = *flag;
    out[O_EIP + e]     = (float)load_ei(ei, e, mode);
    out[O_EIP + E + e] = (float)load_ei(ei, (long long)E + e, mode);
}

extern "C" void kernel_launch(void* const* d_in, const int* in_sizes, int n_in,
                              void* d_out, int out_size, void* d_ws, size_t ws_size,
                              hipStream_t stream) {
    const float* x     = (const float*)d_in[0];
    const void*  ei    = d_in[1];
    const float* xpos  = (const float*)d_in[2];
    const float* iat   = (const float*)d_in[3];
    const float* batch = (const float*)d_in[4];
    const int*   pool  = (const int*)d_in[5];
    float* out = (float*)d_out;
    int* flag = (int*)d_ws;   // only 4 bytes of ws used

    hipMemsetAsync(out + S_CNT, 0, (size_t)M * 4, stream);
    hipMemsetAsync(out + S_BCN, 0, (size_t)NB * 4, stream);
    hipMemsetAsync(out + O_XF,  0, (size_t)M * C * 4, stream);
    hipMemsetAsync(out + O_POS, 0, (size_t)(M * 2 + M * NP + M) * 4, stream);

    k_detect<<<1, 64, 0, stream>>>(ei, flag);
    k_rows<<<(N + 255) / 256, 256, 0, stream>>>(iat, batch, xpos, pool, out);

    long long tx = (long long)N * 32;
    k_xsum<<<(unsigned)((tx + 255) / 256), 256, 0, stream>>>((const float4*)x, out);

    long long tf = (long long)M * 136;
    k_final<<<(unsigned)((tf + 255) / 256), 256, 0, stream>>>(out);

    k_edges<<<(E + 255) / 256, 256, 0, stream>>>(ei, flag, out);
    k_scan<<<1, 1024, 0, stream>>>(out, S_BCN, S_BOF, NB);
    k_scatter<<<(E + 255) / 256, 256, 0, stream>>>(ei, flag, out);
    k_sortcnt<<<(NB + 255) / 256, 256, 0, stream>>>(out);
    k_scan<<<1, 1024, 0, stream>>>(out, S_UCN, S_UOF, NB);
    k_uwrite<<<(NB + 255) / 256, 256, 0, stream>>>(out);
    k_fill<<<(E + 255) / 256, 256, 0, stream>>>(out);
    k_pass<<<(E + 255) / 256, 256, 0, stream>>>(ei, flag, out);
}

// Round 6
// 1624.610 us; speedup vs baseline: 1.3600x; 1.3600x over previous
//
#include <hip/hip_runtime.h>

namespace {
constexpr int N  = 500000;
constexpr int E  = 3000000;
constexpr int C  = 128;
constexpr int M  = 125000;
constexpr int NP = 5;
constexpr int NB = 131072;      // key buckets = top-17 bits of biased int32 key

// d_out flat layout (float32), reference return order:
constexpr long long O_XF  = 0;          // new_xfinal      M*C
constexpr long long O_NEI = 16000000;   // new_edge_index  2*E
constexpr long long O_POS = 22000000;   // new_pos         M*2
constexpr long long O_IAT = 22250000;   // indexatttennew  M*5
constexpr long long O_NB  = 22875000;   // new_batch       M
constexpr long long O_EIP = 23000000;   // edge_index      2*E
constexpr long long O_CL  = 29000000;   // cluster         N
constexpr long long O_BAT = 29500000;   // batch           N

// scratch inside d_out, region [O_EIP, O_EIP+2E) — k_pass (last kernel) is the
// only writer of that region afterwards.
constexpr long long S_CNT = 23000000;   // counts   M ints
constexpr long long S_CLU = 23200000;   // cluster  N ints
constexpr long long S_BCN = 23800000;   // bcnt     NB ints
constexpr long long S_BOF = 24000000;   // boff     NB+1 ints
constexpr long long S_UCN = 24200000;   // ucount   NB ints
constexpr long long S_UOF = 24400000;   // uoff     NB+1 ints
constexpr long long S_COF = 24600000;   // cluster row offsets M+1 ints
constexpr long long S_RPM = 24800000;   // rowperm  N ints (ends 25.3M < 26M)
// bdata (E uints, biased keys) in [O_EIP+E, O_EIP+2E) = row 1 of passthrough.
// key stage (E uints) in O_NEI row 0 [16M,19M) — dead before k_uwrite writes.
}

// mode: 1=int64, 3=float64, 0=int32, 2=float32
__global__ void k_detect(const void* __restrict__ ei, int* __restrict__ flag) {
    if (threadIdx.x != 0 || blockIdx.x != 0) return;
    const unsigned long long* q = (const unsigned long long*)ei;
    unsigned long long hi = 0, lo = 0;
    for (int i = 0; i < 64; ++i) {
        unsigned long long a = q[i];
        unsigned long long b = q[(size_t)E / 2 + i];
        hi |= (a >> 32) | (b >> 32);
        lo |= (a & 0xffffffffULL) | (b & 0xffffffffULL);
    }
    int mode;
    if (hi == 0) mode = 1;
    else if (lo == 0) mode = 3;
    else {
        const int* p = (const int*)ei;
        int ok = 1;
        for (int i = 0; i < 256; ++i) {
            int v0 = p[i], v1 = p[E + i];
            if (v0 < 0 || v0 >= N || v1 < 0 || v1 >= N) ok = 0;
        }
        mode = ok ? 0 : 2;
    }
    *flag = mode;
}

__device__ __forceinline__ int load_ei(const void* ei, long long idx, int mode) {
    long long v;
    if (mode == 1)      v = ((const long long*)ei)[idx];
    else if (mode == 0) v = (long long)((const int*)ei)[idx];
    else if (mode == 3) v = (long long)(((const double*)ei)[idx]);
    else                v = (long long)(((const float*)ei)[idx]);
    if (v < 0 || v >= N) v = 0;
    return (int)v;
}

// int32-wraparound key (JAX x64-disabled semantics), biased so unsigned
// compare == signed compare.
__device__ __forceinline__ unsigned make_key(int c0, int c1) {
    unsigned uv = (unsigned)c0 * (unsigned)M + (unsigned)c1;
    return uv ^ 0x80000000u;
}

// per-row: cluster extract, passthrough outputs, int count histogram
__global__ void k_rows(const float* __restrict__ iat, const float* __restrict__ batch,
                       const int* __restrict__ pool, float* __restrict__ out) {
    int i = blockIdx.x * blockDim.x + threadIdx.x;
    if (i >= N) return;
    int p = pool[0];
    int c = (int)iat[(long long)i * NP + p];
    ((int*)(out + S_CLU))[i] = c;
    out[O_CL + i] = (float)c;
    out[O_BAT + i] = batch[i];
    atomicAdd((int*)(out + S_CNT) + c, 1);
}

// single-block exclusive scan of n ints, outp has n+1 slots
__global__ void k_scan(const float* __restrict__ outbase, long long in_off,
                       long long out_off, int n) {
    const int* in = (const int*)(outbase + in_off);
    int* outp = (int*)(outbase + out_off);
    __shared__ int sh[1024];
    int tid = threadIdx.x;
    int chunk = (n + 1023) / 1024;
    int start = tid * chunk;
    int end = start + chunk;
    if (start > n) start = n;
    if (end > n) end = n;
    int s = 0;
    for (int i = start; i < end; ++i) s += in[i];
    sh[tid] = s;
    __syncthreads();
    for (int off = 1; off < 1024; off <<= 1) {
        int v = (tid >= off) ? sh[tid - off] : 0;
        __syncthreads();
        sh[tid] += v;
        __syncthreads();
    }
    int run = (tid == 0) ? 0 : sh[tid - 1];
    for (int i = start; i < end; ++i) { outp[i] = run; run += in[i]; }
    if (tid == 1023) outp[n] = sh[1023];
}

// group row indices by cluster; S_COF becomes cluster END offsets
__global__ void k_rowscatter(float* __restrict__ out) {
    int i = blockIdx.x * blockDim.x + threadIdx.x;
    if (i >= N) return;
    int c = ((const int*)(out + S_CLU))[i];
    int pos = atomicAdd((int*)(out + S_COF) + c, 1);
    ((int*)(out + S_RPM))[pos] = i;
}

// one wave per cluster: mean of x (lane: 2 cols) + xpos/iat/batch (lanes 0-7)
__global__ void k_xmean(const float2* __restrict__ x2, const float* __restrict__ xpos,
                        const float* __restrict__ iat, const float* __restrict__ batch,
                        float* __restrict__ out) {
    int wid = (int)(((long long)blockIdx.x * blockDim.x + threadIdx.x) >> 6);
    int lane = threadIdx.x & 63;
    if (wid >= M) return;
    const int* coff = (const int*)(out + S_COF);
    int start = (wid == 0) ? 0 : coff[wid - 1];
    int end = coff[wid];
    float cnt = (float)(end - start);
    if (cnt < 1.0f) cnt = 1.0f;
    const int* rpm = (const int*)(out + S_RPM);
    float sx = 0.0f, sy = 0.0f;
    for (int r = start; r < end; ++r) {
        int row = rpm[r];
        float2 v = x2[(long long)row * 64 + lane];
        sx += v.x; sy += v.y;
    }
    float2 o; o.x = sx / cnt; o.y = sy / cnt;
    ((float2*)(out + O_XF))[(long long)wid * 64 + lane] = o;
    if (lane < 8) {
        float s = 0.0f;
        for (int r = start; r < end; ++r) {
            int row = rpm[r];
            float v;
            if (lane < 2)      v = xpos[(long long)row * 2 + lane];
            else if (lane < 7) v = iat[(long long)row * NP + (lane - 2)];
            else               v = batch[row];
            s += v;
        }
        float mres = s / cnt;
        if (lane >= 2) mres = truncf(mres);
        if (lane < 2)      out[O_POS + (long long)wid * 2 + lane] = mres;
        else if (lane < 7) out[O_IAT + (long long)wid * NP + (lane - 2)] = mres;
        else               out[O_NB + wid] = mres;
    }
}

// keys: stage into O_NEI row0 + bucket histogram
__global__ void k_edges(const void* __restrict__ ei, const int* __restrict__ flag,
                        float* __restrict__ out) {
    int e = blockIdx.x * blockDim.x + threadIdx.x;
    if (e >= E) return;
    int mode = *flag;
    const int* cluster = (const int*)(out + S_CLU);
    int c0 = cluster[load_ei(ei, e, mode)];
    int c1 = cluster[load_ei(ei, (long long)E + e, mode)];
    unsigned key = make_key(c0, c1);
    ((unsigned*)(out + O_NEI))[e] = key;
    atomicAdd((int*)(out + S_BCN) + (key >> 15), 1);
}

// scatter staged keys into buckets; S_BOF becomes bucket END afterwards
__global__ void k_scatter(float* __restrict__ out) {
    int e = blockIdx.x * blockDim.x + threadIdx.x;
    if (e >= E) return;
    unsigned key = ((const unsigned*)(out + O_NEI))[e];
    int pos = atomicAdd((int*)(out + S_BOF) + (key >> 15), 1);
    ((unsigned*)(out + O_EIP + E))[pos] = key;
}

__global__ void k_sortcnt(float* __restrict__ out) {
    int m = blockIdx.x * blockDim.x + threadIdx.x;
    if (m >= NB) return;
    const int* boff = (const int*)(out + S_BOF);
    unsigned* bdata = (unsigned*)(out + O_EIP + E);
    int start = (m == 0) ? 0 : boff[m - 1];
    int end = boff[m];
    for (int i = start + 1; i < end; ++i) {
        unsigned v = bdata[i];
        int j = i - 1;
        while (j >= start && bdata[j] > v) { bdata[j + 1] = bdata[j]; --j; }
        bdata[j + 1] = v;
    }
    int u = 0;
    unsigned prev = 0; int has = 0;
    for (int i = start; i < end; ++i) {
        unsigned v = bdata[i];
        if (!has || v != prev) { ++u; prev = v; has = 1; }
    }
    ((int*)(out + S_UCN))[m] = u;
}

// write sorted unique keys decoded via SIGNED floor div/mod (wraparound match)
__global__ void k_uwrite(float* __restrict__ out) {
    int m = blockIdx.x * blockDim.x + threadIdx.x;
    if (m >= NB) return;
    const int* boff = (const int*)(out + S_BOF);
    const unsigned* bdata = (const unsigned*)(out + O_EIP + E);
    int start = (m == 0) ? 0 : boff[m - 1];
    int end = boff[m];
    long long base = ((const int*)(out + S_UOF))[m];
    unsigned prev = 0; int has = 0;
    long long j = 0;
    for (int i = start; i < end; ++i) {
        unsigned v = bdata[i];
        if (!has || v != prev) {
            long long k = (long long)(int)(v ^ 0x80000000u);
            long long r = k % M; if (r < 0) r += M;
            long long q = (k - r) / M;
            out[O_NEI + base + j]     = (float)q;
            out[O_NEI + E + base + j] = (float)r;
            ++j;
            prev = v; has = 1;
        }
    }
}

// tail fill = last sorted unique pair (== keys.max())
__global__ void k_fill(float* __restrict__ out) {
    int p = blockIdx.x * blockDim.x + threadIdx.x;
    if (p >= E) return;
    int U = ((const int*)(out + S_UOF))[NB];
    if (p < U) return;
    float r0 = out[O_NEI + U - 1];
    float r1 = out[O_NEI + E + U - 1];
    out[O_NEI + p]     = r0;
    out[O_NEI + E + p] = r1;
}

// edge_index passthrough — LAST kernel; overwrites all scratch in [23M,29M)
__global__ void k_pass(const void* __restrict__ ei, const int* __restrict__ flag,
                       float* __restrict__ out) {
    int e = blockIdx.x * blockDim.x + threadIdx.x;
    if (e >= E) return;
    int mode = *flag;
    out[O_EIP + e]     = (float)load_ei(ei, e, mode);
    out[O_EIP + E + e] = (float)load_ei(ei, (long long)E + e, mode);
}

extern "C" void kernel_launch(void* const* d_in, const int* in_sizes, int n_in,
                              void* d_out, int out_size, void* d_ws, size_t ws_size,
                              hipStream_t stream) {
    const float* x     = (const float*)d_in[0];
    const void*  ei    = d_in[1];
    const float* xpos  = (const float*)d_in[2];
    const float* iat   = (const float*)d_in[3];
    const float* batch = (const float*)d_in[4];
    const int*   pool  = (const int*)d_in[5];
    float* out = (float*)d_out;
    int* flag = (int*)d_ws;

    hipMemsetAsync(out + S_CNT, 0, (size_t)M * 4, stream);
    hipMemsetAsync(out + S_BCN, 0, (size_t)NB * 4, stream);

    k_detect<<<1, 64, 0, stream>>>(ei, flag);
    k_rows<<<(N + 255) / 256, 256, 0, stream>>>(iat, batch, pool, out);
    k_scan<<<1, 1024, 0, stream>>>(out, S_CNT, S_COF, M);
    k_rowscatter<<<(N + 255) / 256, 256, 0, stream>>>(out);

    long long txm = (long long)M * 64;
    k_xmean<<<(unsigned)((txm + 255) / 256), 256, 0, stream>>>(
        (const float2*)x, xpos, iat, batch, out);

    k_edges<<<(E + 255) / 256, 256, 0, stream>>>(ei, flag, out);
    k_scan<<<1, 1024, 0, stream>>>(out, S_BCN, S_BOF, NB);
    k_scatter<<<(E + 255) / 256, 256, 0, stream>>>(out);
    k_sortcnt<<<(NB + 255) / 256, 256, 0, stream>>>(out);
    k_scan<<<1, 1024, 0, stream>>>(out, S_UCN, S_UOF, NB);
    k_uwrite<<<(NB + 255) / 256, 256, 0, stream>>>(out);
    k_fill<<<(E + 255) / 256, 256, 0, stream>>>(out);
    k_pass<<<(E + 255) / 256, 256, 0, stream>>>(ei, flag, out);
}

// Round 7
// 1017.439 us; speedup vs baseline: 2.1716x; 1.5968x over previous
//
#include <hip/hip_runtime.h>

namespace {
constexpr int N  = 500000;
constexpr int E  = 3000000;
constexpr int C  = 128;
constexpr int M  = 125000;
constexpr int NP = 5;
constexpr int NBK = 1 << 20;    // key buckets = top-20 bits of biased key
constexpr int KSH = 12;         // key >> KSH = bucket
constexpr int ST  = 65536;      // scan level-1/3 threads

// d_out flat layout (float32), reference return order:
constexpr long long O_XF  = 0;          // new_xfinal      M*C
constexpr long long O_NEI = 16000000;   // new_edge_index  2*E
constexpr long long O_POS = 22000000;   // new_pos         M*2
constexpr long long O_IAT = 22250000;   // indexatttennew  M*5
constexpr long long O_NB  = 22875000;   // new_batch       M
constexpr long long O_EIP = 23000000;   // edge_index      2*E
constexpr long long O_CL  = 29000000;   // cluster         N
constexpr long long O_BAT = 29500000;   // batch           N

// ---- scratch overlays inside d_out (all windows time-disjoint) ----
// region B = O_EIP row0 [23M,26M), overwritten only by k_pass (last):
constexpr long long S_CNT = 23000000;   // counts  M ints   (dead after coff scan)
constexpr long long S_CLU = 23130000;   // cluster N ints   (dead after k_edges)
constexpr long long S_COF = 23640000;   // coff    M+1 ints (dead after k_xmean)
constexpr long long S_RPM = 23770000;   // rpm     N ints   (dead after k_xmean)
constexpr long long S_BCN = 24270000;   // bcnt    NBK ints (dead after boff scan)
constexpr long long S_PT  = 25320000;   // scan partials  ST ints
constexpr long long S_PT2 = 25390000;   // scan partials2 ST+1 ints (ends 25455537)
constexpr long long S_BOF = 23000000;   // boff NBK+1 ints — overlays cnt/clu/cof/rpm
constexpr long long S_UOF = 24270000;   // uoff NBK+1 ints — overlays bcnt
// region A = O_NEI row0: staged keys (dead after k_scatter), then:
constexpr long long S_UCN = 16000000;   // ucount NBK ints (dead after uoff scan)
// bdata (E uints) = O_EIP row1 [26M,29M), overwritten only by k_pass.
}

// mode: 1=int64, 3=float64, 0=int32, 2=float32
__global__ void k_detect(const void* __restrict__ ei, int* __restrict__ flag) {
    if (threadIdx.x != 0 || blockIdx.x != 0) return;
    const unsigned long long* q = (const unsigned long long*)ei;
    unsigned long long hi = 0, lo = 0;
    for (int i = 0; i < 64; ++i) {
        unsigned long long a = q[i];
        unsigned long long b = q[(size_t)E / 2 + i];
        hi |= (a >> 32) | (b >> 32);
        lo |= (a & 0xffffffffULL) | (b & 0xffffffffULL);
    }
    int mode;
    if (hi == 0) mode = 1;
    else if (lo == 0) mode = 3;
    else {
        const int* p = (const int*)ei;
        int ok = 1;
        for (int i = 0; i < 256; ++i) {
            int v0 = p[i], v1 = p[E + i];
            if (v0 < 0 || v0 >= N || v1 < 0 || v1 >= N) ok = 0;
        }
        mode = ok ? 0 : 2;
    }
    *flag = mode;
}

__device__ __forceinline__ int load_ei(const void* ei, long long idx, int mode) {
    long long v;
    if (mode == 1)      v = ((const long long*)ei)[idx];
    else if (mode == 0) v = (long long)((const int*)ei)[idx];
    else if (mode == 3) v = (long long)(((const double*)ei)[idx]);
    else                v = (long long)(((const float*)ei)[idx]);
    if (v < 0 || v >= N) v = 0;
    return (int)v;
}

// int32-wraparound key (JAX x64-disabled), biased: unsigned cmp == signed cmp
__device__ __forceinline__ unsigned make_key(int c0, int c1) {
    unsigned uv = (unsigned)c0 * (unsigned)M + (unsigned)c1;
    return uv ^ 0x80000000u;
}

__global__ void k_rows(const float* __restrict__ iat, const float* __restrict__ batch,
                       const int* __restrict__ pool, float* __restrict__ out) {
    int i = blockIdx.x * blockDim.x + threadIdx.x;
    if (i >= N) return;
    int p = pool[0];
    int c = (int)iat[(long long)i * NP + p];
    ((int*)(out + S_CLU))[i] = c;
    out[O_CL + i] = (float)c;
    out[O_BAT + i] = batch[i];
    atomicAdd((int*)(out + S_CNT) + c, 1);
}

// ---- 3-level exclusive scan (outp has n+1 slots) ----
__global__ void k_scan_part(const float* __restrict__ ob, long long in_off, int n) {
    int t = blockIdx.x * blockDim.x + threadIdx.x;
    const int* in = (const int*)(ob + in_off);
    int* pt = (int*)(ob + S_PT);
    int chunk = (n + ST - 1) / ST;
    int s = t * chunk, e = s + chunk;
    if (s > n) s = n;
    if (e > n) e = n;
    int sum = 0;
    for (int i = s; i < e; ++i) sum += in[i];
    pt[t] = sum;
}

// single-block exclusive scan of n ints (n<=65536), outp has n+1 slots
__global__ void k_scan1(const float* __restrict__ ob, long long in_off,
                        long long out_off, int n) {
    const int* in = (const int*)(ob + in_off);
    int* outp = (int*)(ob + out_off);
    __shared__ int sh[1024];
    int tid = threadIdx.x;
    int chunk = (n + 1023) / 1024;
    int start = tid * chunk, end = start + chunk;
    if (start > n) start = n;
    if (end > n) end = n;
    int s = 0;
    for (int i = start; i < end; ++i) s += in[i];
    sh[tid] = s;
    __syncthreads();
    for (int off = 1; off < 1024; off <<= 1) {
        int v = (tid >= off) ? sh[tid - off] : 0;
        __syncthreads();
        sh[tid] += v;
        __syncthreads();
    }
    int run = (tid == 0) ? 0 : sh[tid - 1];
    for (int i = start; i < end; ++i) { outp[i] = run; run += in[i]; }
    if (tid == 1023) outp[n] = sh[1023];
}

__global__ void k_scan_out(const float* __restrict__ ob, long long in_off,
                           long long out_off, int n) {
    int t = blockIdx.x * blockDim.x + threadIdx.x;
    const int* in = (const int*)(ob + in_off);
    int* outp = (int*)(ob + out_off);
    int run = ((const int*)(ob + S_PT2))[t];
    int chunk = (n + ST - 1) / ST;
    int s = t * chunk, e = s + chunk;
    if (s > n) s = n;
    if (e > n) e = n;
    for (int i = s; i < e; ++i) { outp[i] = run; run += in[i]; }
    if (t == ST - 1) outp[n] = run;
}

// group row indices by cluster; S_COF becomes cluster END offsets
__global__ void k_rowscatter(float* __restrict__ out) {
    int i = blockIdx.x * blockDim.x + threadIdx.x;
    if (i >= N) return;
    int c = ((const int*)(out + S_CLU))[i];
    int pos = atomicAdd((int*)(out + S_COF) + c, 1);
    ((int*)(out + S_RPM))[pos] = i;
}

// one wave per cluster: mean of x (lane: 2 cols) + xpos/iat/batch (lanes 0-7)
__global__ void k_xmean(const float2* __restrict__ x2, const float* __restrict__ xpos,
                        const float* __restrict__ iat, const float* __restrict__ batch,
                        float* __restrict__ out) {
    int wid = (int)(((long long)blockIdx.x * blockDim.x + threadIdx.x) >> 6);
    int lane = threadIdx.x & 63;
    if (wid >= M) return;
    const int* coff = (const int*)(out + S_COF);
    int start = (wid == 0) ? 0 : coff[wid - 1];
    int end = coff[wid];
    float cnt = (float)(end - start);
    if (cnt < 1.0f) cnt = 1.0f;
    const int* rpm = (const int*)(out + S_RPM);
    float sx = 0.0f, sy = 0.0f;
    for (int r = start; r < end; ++r) {
        int row = rpm[r];
        float2 v = x2[(long long)row * 64 + lane];
        sx += v.x; sy += v.y;
    }
    float2 o; o.x = sx / cnt; o.y = sy / cnt;
    ((float2*)(out + O_XF))[(long long)wid * 64 + lane] = o;
    if (lane < 8) {
        float s = 0.0f;
        for (int r = start; r < end; ++r) {
            int row = rpm[r];
            float v;
            if (lane < 2)      v = xpos[(long long)row * 2 + lane];
            else if (lane < 7) v = iat[(long long)row * NP + (lane - 2)];
            else               v = batch[row];
            s += v;
        }
        float mres = s / cnt;
        if (lane >= 2) mres = truncf(mres);
        if (lane < 2)      out[O_POS + (long long)wid * 2 + lane] = mres;
        else if (lane < 7) out[O_IAT + (long long)wid * NP + (lane - 2)] = mres;
        else               out[O_NB + wid] = mres;
    }
}

// keys: stage into O_NEI row0 + bucket histogram
__global__ void k_edges(const void* __restrict__ ei, const int* __restrict__ flag,
                        float* __restrict__ out) {
    int e = blockIdx.x * blockDim.x + threadIdx.x;
    if (e >= E) return;
    int mode = *flag;
    const int* cluster = (const int*)(out + S_CLU);
    int c0 = cluster[load_ei(ei, e, mode)];
    int c1 = cluster[load_ei(ei, (long long)E + e, mode)];
    unsigned key = make_key(c0, c1);
    ((unsigned*)(out + O_NEI))[e] = key;
    atomicAdd((int*)(out + S_BCN) + (key >> KSH), 1);
}

// scatter staged keys into buckets; S_BOF becomes bucket END afterwards
__global__ void k_scatter(float* __restrict__ out) {
    int e = blockIdx.x * blockDim.x + threadIdx.x;
    if (e >= E) return;
    unsigned key = ((const unsigned*)(out + O_NEI))[e];
    int pos = atomicAdd((int*)(out + S_BOF) + (key >> KSH), 1);
    ((unsigned*)(out + O_EIP + E))[pos] = key;
}

__global__ void k_sortcnt(float* __restrict__ out) {
    int m = blockIdx.x * blockDim.x + threadIdx.x;
    if (m >= NBK) return;
    const int* boff = (const int*)(out + S_BOF);
    unsigned* bdata = (unsigned*)(out + O_EIP + E);
    int start = (m == 0) ? 0 : boff[m - 1];
    int end = boff[m];
    for (int i = start + 1; i < end; ++i) {
        unsigned v = bdata[i];
        int j = i - 1;
        while (j >= start && bdata[j] > v) { bdata[j + 1] = bdata[j]; --j; }
        bdata[j + 1] = v;
    }
    int u = 0;
    unsigned prev = 0; int has = 0;
    for (int i = start; i < end; ++i) {
        unsigned v = bdata[i];
        if (!has || v != prev) { ++u; prev = v; has = 1; }
    }
    ((int*)(out + S_UCN))[m] = u;
}

// write sorted unique keys decoded via SIGNED floor div/mod (wraparound match)
__global__ void k_uwrite(float* __restrict__ out) {
    int m = blockIdx.x * blockDim.x + threadIdx.x;
    if (m >= NBK) return;
    const int* boff = (const int*)(out + S_BOF);
    const unsigned* bdata = (const unsigned*)(out + O_EIP + E);
    int start = (m == 0) ? 0 : boff[m - 1];
    int end = boff[m];
    long long base = ((const int*)(out + S_UOF))[m];
    unsigned prev = 0; int has = 0;
    long long j = 0;
    for (int i = start; i < end; ++i) {
        unsigned v = bdata[i];
        if (!has || v != prev) {
            long long k = (long long)(int)(v ^ 0x80000000u);
            long long r = k % M; if (r < 0) r += M;
            long long q = (k - r) / M;
            out[O_NEI + base + j]     = (float)q;
            out[O_NEI + E + base + j] = (float)r;
            ++j;
            prev = v; has = 1;
        }
    }
}

// tail fill = last sorted unique pair (== keys.max())
__global__ void k_fill(float* __restrict__ out) {
    int p = blockIdx.x * blockDim.x + threadIdx.x;
    if (p >= E) return;
    int U = ((const int*)(out + S_UOF))[NBK];
    if (p < U) return;
    float r0 = out[O_NEI + U - 1];
    float r1 = out[O_NEI + E + U - 1];
    out[O_NEI + p]     = r0;
    out[O_NEI + E + p] = r1;
}

// edge_index passthrough — LAST kernel; overwrites all scratch in [23M,29M)
__global__ void k_pass(const void* __restrict__ ei, const int* __restrict__ flag,
                       float* __restrict__ out) {
    int e = blockIdx.x * blockDim.x + threadIdx.x;
    if (e >= E) return;
    int mode = *flag;
    out[O_EIP + e]     = (float)load_ei(ei, e, mode);
    out[O_EIP + E + e] = (float)load_ei(ei, (long long)E + e, mode);
}

static inline void scan3(float* out, long long in_off, long long out_off, int n,
                         hipStream_t stream) {
    k_scan_part<<<ST / 256, 256, 0, stream>>>(out, in_off, n);
    k_scan1<<<1, 1024, 0, stream>>>(out, S_PT, S_PT2, ST);
    k_scan_out<<<ST / 256, 256, 0, stream>>>(out, in_off, out_off, n);
}

extern "C" void kernel_launch(void* const* d_in, const int* in_sizes, int n_in,
                              void* d_out, int out_size, void* d_ws, size_t ws_size,
                              hipStream_t stream) {
    const float* x     = (const float*)d_in[0];
    const void*  ei    = d_in[1];
    const float* xpos  = (const float*)d_in[2];
    const float* iat   = (const float*)d_in[3];
    const float* batch = (const float*)d_in[4];
    const int*   pool  = (const int*)d_in[5];
    float* out = (float*)d_out;
    int* flag = (int*)d_ws;

    hipMemsetAsync(out + S_CNT, 0, (size_t)M * 4, stream);

    k_detect<<<1, 64, 0, stream>>>(ei, flag);
    k_rows<<<(N + 255) / 256, 256, 0, stream>>>(iat, batch, pool, out);
    scan3(out, S_CNT, S_COF, M, stream);
    k_rowscatter<<<(N + 255) / 256, 256, 0, stream>>>(out);

    long long txm = (long long)M * 64;
    k_xmean<<<(unsigned)((txm + 255) / 256), 256, 0, stream>>>(
        (const float2*)x, xpos, iat, batch, out);

    // bcnt memset AFTER xmean (bcnt overlays nothing live; cheap 4 MB)
    hipMemsetAsync(out + S_BCN, 0, (size_t)NBK * 4, stream);
    k_edges<<<(E + 255) / 256, 256, 0, stream>>>(ei, flag, out);
    scan3(out, S_BCN, S_BOF, NBK, stream);          // boff overlays dead cnt/clu/cof/rpm
    k_scatter<<<(E + 255) / 256, 256, 0, stream>>>(out);
    k_sortcnt<<<(NBK + 255) / 256, 256, 0, stream>>>(out);
    scan3(out, S_UCN, S_UOF, NBK, stream);          // uoff overlays dead bcnt
    k_uwrite<<<(NBK + 255) / 256, 256, 0, stream>>>(out);
    k_fill<<<(E + 255) / 256, 256, 0, stream>>>(out);
    k_pass<<<(E + 255) / 256, 256, 0, stream>>>(ei, flag, out);
}

// Round 8
// 588.876 us; speedup vs baseline: 3.7521x; 1.7278x over previous
//
#include <hip/hip_runtime.h>

namespace {
constexpr int N  = 500000;
constexpr long long E = 3000000;
constexpr int C  = 128;
constexpr int M  = 125000;
constexpr int NP = 5;
constexpr int ST = 65536;       // scan3 partial threads
constexpr int NC = 512;         // coarse buckets (key >> 23)
constexpr int PMAX = 8192;      // partition pad (max expected ~6.8k)

// d_out flat layout (float32), reference return order:
constexpr long long O_XF  = 0;          // new_xfinal      M*C
constexpr long long O_NEI = 16000000;   // new_edge_index  2*E
constexpr long long O_POS = 22000000;   // new_pos         M*2
constexpr long long O_IAT = 22250000;   // indexatttennew  M*5
constexpr long long O_NB  = 22875000;   // new_batch       M
constexpr long long O_EIP = 23000000;   // edge_index      2*E
constexpr long long O_CL  = 29000000;   // cluster         N
constexpr long long O_BAT = 29500000;   // batch           N

// scratch overlays in region B = O_EIP row0 [23M,26M); k_pass (last) is the
// only later writer. All windows time-disjoint.
constexpr long long S_CNT = 23000000;   // counts  M ints
constexpr long long S_CLU = 23130000;   // cluster N ints
constexpr long long S_COF = 23640000;   // coff    M+1 ints
constexpr long long S_RPM = 23770000;   // rpm     N ints (ends 24.27M)
constexpr long long S_PT  = 25320000;   // scan3 partials  ST
constexpr long long S_PT2 = 25390000;   // scan3 partials2 ST+1
constexpr long long S_CBN = 25500000;   // coarse counts NC
constexpr long long S_CBS = 25501000;   // cbase NC+1
constexpr long long S_CPS = 25502000;   // cpos  NC (running reservation)
constexpr long long S_UCT = 25503000;   // ucount NC
constexpr long long S_UOF = 25504000;   // uoff  NC+1
// staged keys (E u32)  = O_NEI row0 [16M,19M), dead after k_part
// bdata (E u32)        = O_EIP row1 [26M,29M), dead after k_uwrite2
}

// mode: 1=int64, 3=float64, 0=int32, 2=float32
__global__ void k_detect(const void* __restrict__ ei, int* __restrict__ flag) {
    if (threadIdx.x != 0 || blockIdx.x != 0) return;
    const unsigned long long* q = (const unsigned long long*)ei;
    unsigned long long hi = 0, lo = 0;
    for (int i = 0; i < 64; ++i) {
        unsigned long long a = q[i];
        unsigned long long b = q[(size_t)E / 2 + i];
        hi |= (a >> 32) | (b >> 32);
        lo |= (a & 0xffffffffULL) | (b & 0xffffffffULL);
    }
    int mode;
    if (hi == 0) mode = 1;
    else if (lo == 0) mode = 3;
    else {
        const int* p = (const int*)ei;
        int ok = 1;
        for (int i = 0; i < 256; ++i) {
            int v0 = p[i], v1 = p[E + i];
            if (v0 < 0 || v0 >= N || v1 < 0 || v1 >= N) ok = 0;
        }
        mode = ok ? 0 : 2;
    }
    *flag = mode;
}

__device__ __forceinline__ int load_ei(const void* ei, long long idx, int mode) {
    long long v;
    if (mode == 1)      v = ((const long long*)ei)[idx];
    else if (mode == 0) v = (long long)((const int*)ei)[idx];
    else if (mode == 3) v = (long long)(((const double*)ei)[idx]);
    else                v = (long long)(((const float*)ei)[idx]);
    if (v < 0 || v >= N) v = 0;
    return (int)v;
}

// int32-wraparound key (JAX x64-disabled), biased: unsigned cmp == signed cmp
__device__ __forceinline__ unsigned make_key(int c0, int c1) {
    unsigned uv = (unsigned)c0 * (unsigned)M + (unsigned)c1;
    return uv ^ 0x80000000u;
}

__global__ void k_rows(const float* __restrict__ iat, const float* __restrict__ batch,
                       const int* __restrict__ pool, float* __restrict__ out) {
    int i = blockIdx.x * blockDim.x + threadIdx.x;
    if (i >= N) return;
    int p = pool[0];
    int c = (int)iat[(long long)i * NP + p];
    ((int*)(out + S_CLU))[i] = c;
    out[O_CL + i] = (float)c;
    out[O_BAT + i] = batch[i];
    atomicAdd((int*)(out + S_CNT) + c, 1);
}

// ---- 3-level exclusive scan for coff (M elements) ----
__global__ void k_scan_part(const float* __restrict__ ob, long long in_off, int n) {
    int t = blockIdx.x * blockDim.x + threadIdx.x;
    const int* in = (const int*)(ob + in_off);
    int* pt = (int*)(ob + S_PT);
    int chunk = (n + ST - 1) / ST;
    int s = t * chunk, e = s + chunk;
    if (s > n) s = n;
    if (e > n) e = n;
    int sum = 0;
    for (int i = s; i < e; ++i) sum += in[i];
    pt[t] = sum;
}

__global__ void k_scan1(const float* __restrict__ ob, long long in_off,
                        long long out_off, int n) {
    const int* in = (const int*)(ob + in_off);
    int* outp = (int*)(ob + out_off);
    __shared__ int sh[1024];
    int tid = threadIdx.x;
    int chunk = (n + 1023) / 1024;
    int start = tid * chunk, end = start + chunk;
    if (start > n) start = n;
    if (end > n) end = n;
    int s = 0;
    for (int i = start; i < end; ++i) s += in[i];
    sh[tid] = s;
    __syncthreads();
    for (int off = 1; off < 1024; off <<= 1) {
        int v = (tid >= off) ? sh[tid - off] : 0;
        __syncthreads();
        sh[tid] += v;
        __syncthreads();
    }
    int run = (tid == 0) ? 0 : sh[tid - 1];
    for (int i = start; i < end; ++i) { outp[i] = run; run += in[i]; }
    if (tid == 1023) outp[n] = sh[1023];
}

__global__ void k_scan_out(const float* __restrict__ ob, long long in_off,
                           long long out_off, int n) {
    int t = blockIdx.x * blockDim.x + threadIdx.x;
    const int* in = (const int*)(ob + in_off);
    int* outp = (int*)(ob + out_off);
    int run = ((const int*)(ob + S_PT2))[t];
    int chunk = (n + ST - 1) / ST;
    int s = t * chunk, e = s + chunk;
    if (s > n) s = n;
    if (e > n) e = n;
    for (int i = s; i < e; ++i) { outp[i] = run; run += in[i]; }
    if (t == ST - 1) outp[n] = run;
}

__global__ void k_rowscatter(float* __restrict__ out) {
    int i = blockIdx.x * blockDim.x + threadIdx.x;
    if (i >= N) return;
    int c = ((const int*)(out + S_CLU))[i];
    int pos = atomicAdd((int*)(out + S_COF) + c, 1);
    ((int*)(out + S_RPM))[pos] = i;
}

// one wave per cluster: mean of x (lane: 2 cols) + xpos/iat/batch (lanes 0-7)
__global__ void k_xmean(const float2* __restrict__ x2, const float* __restrict__ xpos,
                        const float* __restrict__ iat, const float* __restrict__ batch,
                        float* __restrict__ out) {
    int wid = (int)(((long long)blockIdx.x * blockDim.x + threadIdx.x) >> 6);
    int lane = threadIdx.x & 63;
    if (wid >= M) return;
    const int* coff = (const int*)(out + S_COF);
    int start = (wid == 0) ? 0 : coff[wid - 1];
    int end = coff[wid];
    float cnt = (float)(end - start);
    if (cnt < 1.0f) cnt = 1.0f;
    const int* rpm = (const int*)(out + S_RPM);
    float sx = 0.0f, sy = 0.0f;
    for (int r = start; r < end; ++r) {
        int row = rpm[r];
        float2 v = x2[(long long)row * 64 + lane];
        sx += v.x; sy += v.y;
    }
    float2 o; o.x = sx / cnt; o.y = sy / cnt;
    ((float2*)(out + O_XF))[(long long)wid * 64 + lane] = o;
    if (lane < 8) {
        float s = 0.0f;
        for (int r = start; r < end; ++r) {
            int row = rpm[r];
            float v;
            if (lane < 2)      v = xpos[(long long)row * 2 + lane];
            else if (lane < 7) v = iat[(long long)row * NP + (lane - 2)];
            else               v = batch[row];
            s += v;
        }
        float mres = s / cnt;
        if (lane >= 2) mres = truncf(mres);
        if (lane < 2)      out[O_POS + (long long)wid * 2 + lane] = mres;
        else if (lane < 7) out[O_IAT + (long long)wid * NP + (lane - 2)] = mres;
        else               out[O_NB + wid] = mres;
    }
}

// stage keys + LDS-aggregated coarse histogram (512 buckets, top-9 bits)
__global__ __launch_bounds__(256) void k_edges2(const void* __restrict__ ei,
                                                const int* __restrict__ flag,
                                                float* __restrict__ out) {
    __shared__ int h[NC];
    int tid = threadIdx.x;
    long long cb = (long long)blockIdx.x * 4096;
    for (int s = tid; s < NC; s += 256) h[s] = 0;
    __syncthreads();
    int mode = *flag;
    const int* cluster = (const int*)(out + S_CLU);
    unsigned* stage = (unsigned*)(out + O_NEI);
    for (int s = 0; s < 16; ++s) {
        long long i = cb + s * 256 + tid;
        if (i < E) {
            int c0 = cluster[load_ei(ei, i, mode)];
            int c1 = cluster[load_ei(ei, E + i, mode)];
            unsigned key = make_key(c0, c1);
            stage[i] = key;
            atomicAdd(&h[key >> 23], 1);
        }
    }
    __syncthreads();
    for (int s = tid; s < NC; s += 256) {
        int v = h[s];
        if (v) atomicAdd((int*)(out + S_CBN) + s, v);
    }
}

// single-block exclusive scan of NC=512; also optionally seeds cpos
__global__ void k_scan512(float* __restrict__ out, long long in_off,
                          long long out_off, long long pos_off) {
    __shared__ int sh[NC];
    int tid = threadIdx.x;
    const int* in = (const int*)(out + in_off);
    int* o = (int*)(out + out_off);
    int v0 = in[tid];
    sh[tid] = v0;
    __syncthreads();
    for (int off = 1; off < NC; off <<= 1) {
        int v = (tid >= off) ? sh[tid - off] : 0;
        __syncthreads();
        sh[tid] += v;
        __syncthreads();
    }
    int excl = sh[tid] - v0;
    o[tid] = excl;
    if (pos_off >= 0) ((int*)(out + pos_off))[tid] = excl;
    if (tid == NC - 1) o[NC] = sh[NC - 1];
}

// LDS-aggregated partition: group 4096 staged keys by coarse bucket, reserve
// global runs (1 atomic per block-bucket), write contiguous runs into bdata
__global__ __launch_bounds__(512) void k_part(float* __restrict__ out) {
    __shared__ int h[NC], h2[NC], lb[NC], gb[NC];
    __shared__ unsigned g[4096];
    __shared__ int d[4096];
    int tid = threadIdx.x;
    long long cb = (long long)blockIdx.x * 4096;
    const unsigned* stage = (const unsigned*)(out + O_NEI);
    unsigned* bdata = (unsigned*)(out + O_EIP + E);
    if (tid < NC) { h[tid] = 0; h2[tid] = 0; }
    __syncthreads();
    unsigned keys[8];
    for (int s = 0; s < 8; ++s) {
        long long i = cb + s * 512 + tid;
        if (i < E) {
            unsigned key = stage[i];
            keys[s] = key;
            atomicAdd(&h[key >> 23], 1);
        }
    }
    __syncthreads();
    if (tid < NC) lb[tid] = h[tid];
    __syncthreads();
    for (int off = 1; off < NC; off <<= 1) {
        int v = (tid < NC && tid >= off) ? lb[tid - off] : 0;
        __syncthreads();
        if (tid < NC) lb[tid] += v;
        __syncthreads();
    }
    if (tid < NC) {
        int excl = lb[tid] - h[tid];
        gb[tid] = atomicAdd((int*)(out + S_CPS) + tid, h[tid]);
        lb[tid] = excl;
    }
    __syncthreads();
    for (int s = 0; s < 8; ++s) {
        long long i = cb + s * 512 + tid;
        if (i < E) {
            unsigned key = keys[s];
            int b = key >> 23;
            int r = atomicAdd(&h2[b], 1);
            int slot = lb[b] + r;
            g[slot] = key;
            d[slot] = gb[b] + r;
        }
    }
    __syncthreads();
    int tot = (int)((E - cb < 4096) ? (E - cb) : 4096);
    for (int s = 0; s < 8; ++s) {
        int slot = tid + s * 512;
        if (slot < tot) bdata[d[slot]] = g[slot];
    }
}

// per-partition in-LDS bitonic sort + dedupe-compact, write back in place
__global__ __launch_bounds__(1024) void k_psort(float* __restrict__ out) {
    __shared__ unsigned sk[PMAX];
    __shared__ int ssc[1024];
    int p = blockIdx.x;
    int tid = threadIdx.x;
    const int* cbase = (const int*)(out + S_CBS);
    int base = cbase[p];
    int n = cbase[p + 1] - base;
    if (n > PMAX) n = PMAX;   // unreachable guard
    unsigned* bdata = (unsigned*)(out + O_EIP + E);
    for (int i = tid; i < PMAX; i += 1024)
        sk[i] = (i < n) ? bdata[base + i] : 0xFFFFFFFFu;
    __syncthreads();
    for (int k = 2; k <= PMAX; k <<= 1) {
        for (int j = k >> 1; j > 0; j >>= 1) {
            for (int i = tid; i < PMAX; i += 1024) {
                int ixj = i ^ j;
                if (ixj > i) {
                    unsigned a = sk[i], b = sk[ixj];
                    bool up = ((i & k) == 0);
                    if ((a > b) == up) { sk[i] = b; sk[ixj] = a; }
                }
            }
            __syncthreads();
        }
    }
    int c = 0;
    for (int s = 0; s < PMAX / 1024; ++s) {
        int i = tid * (PMAX / 1024) + s;
        bool v = (i < n) && (i == 0 || sk[i] != sk[i - 1]);
        c += v ? 1 : 0;
    }
    ssc[tid] = c;
    __syncthreads();
    for (int off = 1; off < 1024; off <<= 1) {
        int v = (tid >= off) ? ssc[tid - off] : 0;
        __syncthreads();
        ssc[tid] += v;
        __syncthreads();
    }
    int pos = ssc[tid] - c;
    for (int s = 0; s < PMAX / 1024; ++s) {
        int i = tid * (PMAX / 1024) + s;
        bool v = (i < n) && (i == 0 || sk[i] != sk[i - 1]);
        if (v) bdata[base + pos++] = sk[i];
    }
    if (tid == 1023) ((int*)(out + S_UCT))[p] = ssc[1023];
}

// copy each partition's sorted unique keys to final position, decoded
__global__ __launch_bounds__(256) void k_uwrite2(float* __restrict__ out) {
    int p = blockIdx.x;
    int tid = threadIdx.x;
    int base = ((const int*)(out + S_CBS))[p];
    int u    = ((const int*)(out + S_UCT))[p];
    long long dst = ((const int*)(out + S_UOF))[p];
    const unsigned* bdata = (const unsigned*)(out + O_EIP + E);
    for (int i = tid; i < u; i += 256) {
        unsigned v = bdata[base + i];
        long long k = (long long)(int)(v ^ 0x80000000u);
        long long r = k % M; if (r < 0) r += M;
        long long q = (k - r) / M;
        out[O_NEI + dst + i]     = (float)q;
        out[O_NEI + E + dst + i] = (float)r;
    }
}

// tail fill = last sorted unique pair (== keys.max())
__global__ void k_fill(float* __restrict__ out) {
    int p = blockIdx.x * blockDim.x + threadIdx.x;
    if (p >= E) return;
    int U = ((const int*)(out + S_UOF))[NC];
    if (p < U) return;
    float r0 = out[O_NEI + U - 1];
    float r1 = out[O_NEI + E + U - 1];
    out[O_NEI + p]     = r0;
    out[O_NEI + E + p] = r1;
}

// edge_index passthrough — LAST kernel; overwrites all scratch in [23M,29M)
__global__ void k_pass(const void* __restrict__ ei, const int* __restrict__ flag,
                       float* __restrict__ out) {
    int e = blockIdx.x * blockDim.x + threadIdx.x;
    if (e >= E) return;
    int mode = *flag;
    out[O_EIP + e]     = (float)load_ei(ei, e, mode);
    out[O_EIP + E + e] = (float)load_ei(ei, E + e, mode);
}

static inline void scan3(float* out, long long in_off, long long out_off, int n,
                         hipStream_t stream) {
    k_scan_part<<<ST / 256, 256, 0, stream>>>(out, in_off, n);
    k_scan1<<<1, 1024, 0, stream>>>(out, S_PT, S_PT2, ST);
    k_scan_out<<<ST / 256, 256, 0, stream>>>(out, in_off, out_off, n);
}

extern "C" void kernel_launch(void* const* d_in, const int* in_sizes, int n_in,
                              void* d_out, int out_size, void* d_ws, size_t ws_size,
                              hipStream_t stream) {
    const float* x     = (const float*)d_in[0];
    const void*  ei    = d_in[1];
    const float* xpos  = (const float*)d_in[2];
    const float* iat   = (const float*)d_in[3];
    const float* batch = (const float*)d_in[4];
    const int*   pool  = (const int*)d_in[5];
    float* out = (float*)d_out;
    int* flag = (int*)d_ws;

    int eblocks = (int)((E + 4095) / 4096);   // 733

    hipMemsetAsync(out + S_CNT, 0, (size_t)M * 4, stream);
    hipMemsetAsync(out + S_CBN, 0, (size_t)NC * 4, stream);

    k_detect<<<1, 64, 0, stream>>>(ei, flag);
    k_rows<<<(N + 255) / 256, 256, 0, stream>>>(iat, batch, pool, out);
    scan3(out, S_CNT, S_COF, M, stream);
    k_rowscatter<<<(N + 255) / 256, 256, 0, stream>>>(out);

    long long txm = (long long)M * 64;
    k_xmean<<<(unsigned)((txm + 255) / 256), 256, 0, stream>>>(
        (const float2*)x, xpos, iat, batch, out);

    k_edges2<<<eblocks, 256, 0, stream>>>(ei, flag, out);
    k_scan512<<<1, NC, 0, stream>>>(out, S_CBN, S_CBS, S_CPS);
    k_part<<<eblocks, 512, 0, stream>>>(out);
    k_psort<<<NC, 1024, 0, stream>>>(out);
    k_scan512<<<1, NC, 0, stream>>>(out, S_UCT, S_UOF, -1);
    k_uwrite2<<<NC, 256, 0, stream>>>(out);
    k_fill<<<(unsigned)((E + 255) / 256), 256, 0, stream>>>(out);
    k_pass<<<(unsigned)((E + 255) / 256), 256, 0, stream>>>(ei, flag, out);
}

// Round 9
// 560.989 us; speedup vs baseline: 3.9386x; 1.0497x over previous
//
#include <hip/hip_runtime.h>

namespace {
constexpr int N  = 500000;
constexpr long long E = 3000000;
constexpr int C  = 128;
constexpr int M  = 125000;
constexpr int NP = 5;
constexpr int ST = 65536;       // scan3 partial threads
constexpr int NC = 512;         // coarse buckets (key >> 23)
constexpr int PMAX = 8192;      // partition pad (max expected ~6.8k)

// d_out flat layout (float32), reference return order:
constexpr long long O_XF  = 0;          // new_xfinal      M*C
constexpr long long O_NEI = 16000000;   // new_edge_index  2*E
constexpr long long O_POS = 22000000;   // new_pos         M*2
constexpr long long O_IAT = 22250000;   // indexatttennew  M*5
constexpr long long O_NB  = 22875000;   // new_batch       M
constexpr long long O_EIP = 23000000;   // edge_index      2*E
constexpr long long O_CL  = 29000000;   // cluster         N
constexpr long long O_BAT = 29500000;   // batch           N

// scratch overlays in region B = O_EIP row0 [23M,26M); k_pass (last) is the
// only later writer. All windows time-disjoint.
constexpr long long S_CNT = 23000000;   // counts  M ints
constexpr long long S_CLU = 23130000;   // cluster N ints
constexpr long long S_COF = 23640000;   // coff    M+1 ints
constexpr long long S_RPM = 23770000;   // rpm     N ints (ends 24.27M)
constexpr long long S_PT  = 25320000;   // scan3 partials  ST
constexpr long long S_PT2 = 25390000;   // scan3 partials2 ST+1
constexpr long long S_CBN = 25500000;   // coarse counts NC
constexpr long long S_CBS = 25501000;   // cbase NC+1
constexpr long long S_CPS = 25502000;   // cpos  NC (running reservation)
constexpr long long S_UCT = 25503000;   // ucount NC
constexpr long long S_UOF = 25504000;   // uoff  NC+1
// staged keys (E u32)  = O_NEI row0 [16M,19M), dead after k_part
// bdata (E u32)        = O_EIP row1 [26M,29M), dead after k_uwrite2
}

// mode: 1=int64, 3=float64, 0=int32, 2=float32
__global__ void k_detect(const void* __restrict__ ei, int* __restrict__ flag) {
    if (threadIdx.x != 0 || blockIdx.x != 0) return;
    const unsigned long long* q = (const unsigned long long*)ei;
    unsigned long long hi = 0, lo = 0;
    for (int i = 0; i < 64; ++i) {
        unsigned long long a = q[i];
        unsigned long long b = q[(size_t)E / 2 + i];
        hi |= (a >> 32) | (b >> 32);
        lo |= (a & 0xffffffffULL) | (b & 0xffffffffULL);
    }
    int mode;
    if (hi == 0) mode = 1;
    else if (lo == 0) mode = 3;
    else {
        const int* p = (const int*)ei;
        int ok = 1;
        for (int i = 0; i < 256; ++i) {
            int v0 = p[i], v1 = p[E + i];
            if (v0 < 0 || v0 >= N || v1 < 0 || v1 >= N) ok = 0;
        }
        mode = ok ? 0 : 2;
    }
    *flag = mode;
}

__device__ __forceinline__ int load_ei(const void* ei, long long idx, int mode) {
    long long v;
    if (mode == 1)      v = ((const long long*)ei)[idx];
    else if (mode == 0) v = (long long)((const int*)ei)[idx];
    else if (mode == 3) v = (long long)(((const double*)ei)[idx]);
    else                v = (long long)(((const float*)ei)[idx]);
    if (v < 0 || v >= N) v = 0;
    return (int)v;
}

// int32-wraparound key (JAX x64-disabled), biased: unsigned cmp == signed cmp
__device__ __forceinline__ unsigned make_key(int c0, int c1) {
    unsigned uv = (unsigned)c0 * (unsigned)M + (unsigned)c1;
    return uv ^ 0x80000000u;
}

__global__ void k_rows(const float* __restrict__ iat, const float* __restrict__ batch,
                       const int* __restrict__ pool, float* __restrict__ out) {
    int i = blockIdx.x * blockDim.x + threadIdx.x;
    if (i >= N) return;
    int p = pool[0];
    int c = (int)iat[(long long)i * NP + p];
    ((int*)(out + S_CLU))[i] = c;
    out[O_CL + i] = (float)c;
    out[O_BAT + i] = batch[i];
    atomicAdd((int*)(out + S_CNT) + c, 1);
}

// ---- 3-level exclusive scan for coff (M elements) ----
__global__ void k_scan_part(const float* __restrict__ ob, long long in_off, int n) {
    int t = blockIdx.x * blockDim.x + threadIdx.x;
    const int* in = (const int*)(ob + in_off);
    int* pt = (int*)(ob + S_PT);
    int chunk = (n + ST - 1) / ST;
    int s = t * chunk, e = s + chunk;
    if (s > n) s = n;
    if (e > n) e = n;
    int sum = 0;
    for (int i = s; i < e; ++i) sum += in[i];
    pt[t] = sum;
}

__global__ void k_scan1(const float* __restrict__ ob, long long in_off,
                        long long out_off, int n) {
    const int* in = (const int*)(ob + in_off);
    int* outp = (int*)(ob + out_off);
    __shared__ int sh[1024];
    int tid = threadIdx.x;
    int chunk = (n + 1023) / 1024;
    int start = tid * chunk, end = start + chunk;
    if (start > n) start = n;
    if (end > n) end = n;
    int s = 0;
    for (int i = start; i < end; ++i) s += in[i];
    sh[tid] = s;
    __syncthreads();
    for (int off = 1; off < 1024; off <<= 1) {
        int v = (tid >= off) ? sh[tid - off] : 0;
        __syncthreads();
        sh[tid] += v;
        __syncthreads();
    }
    int run = (tid == 0) ? 0 : sh[tid - 1];
    for (int i = start; i < end; ++i) { outp[i] = run; run += in[i]; }
    if (tid == 1023) outp[n] = sh[1023];
}

__global__ void k_scan_out(const float* __restrict__ ob, long long in_off,
                           long long out_off, int n) {
    int t = blockIdx.x * blockDim.x + threadIdx.x;
    const int* in = (const int*)(ob + in_off);
    int* outp = (int*)(ob + out_off);
    int run = ((const int*)(ob + S_PT2))[t];
    int chunk = (n + ST - 1) / ST;
    int s = t * chunk, e = s + chunk;
    if (s > n) s = n;
    if (e > n) e = n;
    for (int i = s; i < e; ++i) { outp[i] = run; run += in[i]; }
    if (t == ST - 1) outp[n] = run;
}

__global__ void k_rowscatter(float* __restrict__ out) {
    int i = blockIdx.x * blockDim.x + threadIdx.x;
    if (i >= N) return;
    int c = ((const int*)(out + S_CLU))[i];
    int pos = atomicAdd((int*)(out + S_COF) + c, 1);
    ((int*)(out + S_RPM))[pos] = i;
}

// one wave per cluster; 2 rows in flight per iteration (half-wave each,
// float4/lane = 16B), cross-half combine via shfl_xor(32)
__global__ void k_xmean(const float4* __restrict__ x4, const float* __restrict__ xpos,
                        const float* __restrict__ iat, const float* __restrict__ batch,
                        float* __restrict__ out) {
    int wid = (int)(((long long)blockIdx.x * blockDim.x + threadIdx.x) >> 6);
    int lane = threadIdx.x & 63;
    if (wid >= M) return;
    const int* coff = (const int*)(out + S_COF);
    int start = (wid == 0) ? 0 : coff[wid - 1];
    int end = coff[wid];
    float cnt = (float)(end - start);
    if (cnt < 1.0f) cnt = 1.0f;
    const int* rpm = (const int*)(out + S_RPM);
    int half = lane >> 5;     // 0: even rows, 1: odd rows
    int sub  = lane & 31;     // float4 column group
    float4 acc = make_float4(0.f, 0.f, 0.f, 0.f);
    for (int r = start + half; r < end; r += 2) {
        int row = rpm[r];
        float4 v = x4[(long long)row * 32 + sub];
        acc.x += v.x; acc.y += v.y; acc.z += v.z; acc.w += v.w;
    }
    // combine halves: lane i += lane i^32
    acc.x += __shfl_xor(acc.x, 32, 64);
    acc.y += __shfl_xor(acc.y, 32, 64);
    acc.z += __shfl_xor(acc.z, 32, 64);
    acc.w += __shfl_xor(acc.w, 32, 64);
    if (half == 0) {
        float4 o;
        o.x = acc.x / cnt; o.y = acc.y / cnt; o.z = acc.z / cnt; o.w = acc.w / cnt;
        ((float4*)(out + O_XF))[(long long)wid * 32 + sub] = o;
    } else if (sub < 8) {
        // small columns on the otherwise-idle half: xpos(2), iat(5), batch(1)
        int lc = sub;
        float s = 0.0f;
        for (int r = start; r < end; ++r) {
            int row = rpm[r];
            float v;
            if (lc < 2)      v = xpos[(long long)row * 2 + lc];
            else if (lc < 7) v = iat[(long long)row * NP + (lc - 2)];
            else             v = batch[row];
            s += v;
        }
        float mres = s / cnt;
        if (lc >= 2) mres = truncf(mres);
        if (lc < 2)      out[O_POS + (long long)wid * 2 + lc] = mres;
        else if (lc < 7) out[O_IAT + (long long)wid * NP + (lc - 2)] = mres;
        else             out[O_NB + wid] = mres;
    }
}

// stage keys + LDS-aggregated coarse histogram (512 buckets, top-9 bits)
__global__ __launch_bounds__(256) void k_edges2(const void* __restrict__ ei,
                                                const int* __restrict__ flag,
                                                float* __restrict__ out) {
    __shared__ int h[NC];
    int tid = threadIdx.x;
    long long cb = (long long)blockIdx.x * 4096;
    for (int s = tid; s < NC; s += 256) h[s] = 0;
    __syncthreads();
    int mode = *flag;
    const int* cluster = (const int*)(out + S_CLU);
    unsigned* stage = (unsigned*)(out + O_NEI);
    for (int s = 0; s < 16; ++s) {
        long long i = cb + s * 256 + tid;
        if (i < E) {
            int c0 = cluster[load_ei(ei, i, mode)];
            int c1 = cluster[load_ei(ei, E + i, mode)];
            unsigned key = make_key(c0, c1);
            stage[i] = key;
            atomicAdd(&h[key >> 23], 1);
        }
    }
    __syncthreads();
    for (int s = tid; s < NC; s += 256) {
        int v = h[s];
        if (v) atomicAdd((int*)(out + S_CBN) + s, v);
    }
}

// single-block exclusive scan of NC=512; also optionally seeds cpos
__global__ void k_scan512(float* __restrict__ out, long long in_off,
                          long long out_off, long long pos_off) {
    __shared__ int sh[NC];
    int tid = threadIdx.x;
    const int* in = (const int*)(out + in_off);
    int* o = (int*)(out + out_off);
    int v0 = in[tid];
    sh[tid] = v0;
    __syncthreads();
    for (int off = 1; off < NC; off <<= 1) {
        int v = (tid >= off) ? sh[tid - off] : 0;
        __syncthreads();
        sh[tid] += v;
        __syncthreads();
    }
    int excl = sh[tid] - v0;
    o[tid] = excl;
    if (pos_off >= 0) ((int*)(out + pos_off))[tid] = excl;
    if (tid == NC - 1) o[NC] = sh[NC - 1];
}

// LDS-aggregated partition: group 4096 staged keys by coarse bucket, reserve
// global runs (1 atomic per block-bucket), write contiguous runs into bdata
__global__ __launch_bounds__(512) void k_part(float* __restrict__ out) {
    __shared__ int h[NC], h2[NC], lb[NC], gb[NC];
    __shared__ unsigned g[4096];
    __shared__ int d[4096];
    int tid = threadIdx.x;
    long long cb = (long long)blockIdx.x * 4096;
    const unsigned* stage = (const unsigned*)(out + O_NEI);
    unsigned* bdata = (unsigned*)(out + O_EIP + E);
    if (tid < NC) { h[tid] = 0; h2[tid] = 0; }
    __syncthreads();
    unsigned keys[8];
    for (int s = 0; s < 8; ++s) {
        long long i = cb + s * 512 + tid;
        if (i < E) {
            unsigned key = stage[i];
            keys[s] = key;
            atomicAdd(&h[key >> 23], 1);
        }
    }
    __syncthreads();
    if (tid < NC) lb[tid] = h[tid];
    __syncthreads();
    for (int off = 1; off < NC; off <<= 1) {
        int v = (tid < NC && tid >= off) ? lb[tid - off] : 0;
        __syncthreads();
        if (tid < NC) lb[tid] += v;
        __syncthreads();
    }
    if (tid < NC) {
        int excl = lb[tid] - h[tid];
        gb[tid] = atomicAdd((int*)(out + S_CPS) + tid, h[tid]);
        lb[tid] = excl;
    }
    __syncthreads();
    for (int s = 0; s < 8; ++s) {
        long long i = cb + s * 512 + tid;
        if (i < E) {
            unsigned key = keys[s];
            int b = key >> 23;
            int r = atomicAdd(&h2[b], 1);
            int slot = lb[b] + r;
            g[slot] = key;
            d[slot] = gb[b] + r;
        }
    }
    __syncthreads();
    int tot = (int)((E - cb < 4096) ? (E - cb) : 4096);
    for (int s = 0; s < 8; ++s) {
        int slot = tid + s * 512;
        if (slot < tot) bdata[d[slot]] = g[slot];
    }
}

// per-partition in-LDS bitonic sort + dedupe-compact, write back in place
__global__ __launch_bounds__(1024) void k_psort(float* __restrict__ out) {
    __shared__ unsigned sk[PMAX];
    __shared__ int ssc[1024];
    int p = blockIdx.x;
    int tid = threadIdx.x;
    const int* cbase = (const int*)(out + S_CBS);
    int base = cbase[p];
    int n = cbase[p + 1] - base;
    if (n > PMAX) n = PMAX;   // unreachable guard
    unsigned* bdata = (unsigned*)(out + O_EIP + E);
    for (int i = tid; i < PMAX; i += 1024)
        sk[i] = (i < n) ? bdata[base + i] : 0xFFFFFFFFu;
    __syncthreads();
    for (int k = 2; k <= PMAX; k <<= 1) {
        for (int j = k >> 1; j > 0; j >>= 1) {
            for (int i = tid; i < PMAX; i += 1024) {
                int ixj = i ^ j;
                if (ixj > i) {
                    unsigned a = sk[i], b = sk[ixj];
                    bool up = ((i & k) == 0);
                    if ((a > b) == up) { sk[i] = b; sk[ixj] = a; }
                }
            }
            __syncthreads();
        }
    }
    int c = 0;
    for (int s = 0; s < PMAX / 1024; ++s) {
        int i = tid * (PMAX / 1024) + s;
        bool v = (i < n) && (i == 0 || sk[i] != sk[i - 1]);
        c += v ? 1 : 0;
    }
    ssc[tid] = c;
    __syncthreads();
    for (int off = 1; off < 1024; off <<= 1) {
        int v = (tid >= off) ? ssc[tid - off] : 0;
        __syncthreads();
        ssc[tid] += v;
        __syncthreads();
    }
    int pos = ssc[tid] - c;
    for (int s = 0; s < PMAX / 1024; ++s) {
        int i = tid * (PMAX / 1024) + s;
        bool v = (i < n) && (i == 0 || sk[i] != sk[i - 1]);
        if (v) bdata[base + pos++] = sk[i];
    }
    if (tid == 1023) ((int*)(out + S_UCT))[p] = ssc[1023];
}

// copy each partition's sorted unique keys to final position, decoded
__global__ __launch_bounds__(256) void k_uwrite2(float* __restrict__ out) {
    int p = blockIdx.x;
    int tid = threadIdx.x;
    int base = ((const int*)(out + S_CBS))[p];
    int u    = ((const int*)(out + S_UCT))[p];
    long long dst = ((const int*)(out + S_UOF))[p];
    const unsigned* bdata = (const unsigned*)(out + O_EIP + E);
    for (int i = tid; i < u; i += 256) {
        unsigned v = bdata[base + i];
        long long k = (long long)(int)(v ^ 0x80000000u);
        long long r = k % M; if (r < 0) r += M;
        long long q = (k - r) / M;
        out[O_NEI + dst + i]     = (float)q;
        out[O_NEI + E + dst + i] = (float)r;
    }
}

// tail fill = last sorted unique pair (== keys.max())
__global__ void k_fill(float* __restrict__ out) {
    int p = blockIdx.x * blockDim.x + threadIdx.x;
    if (p >= E) return;
    int U = ((const int*)(out + S_UOF))[NC];
    if (p < U) return;
    float r0 = out[O_NEI + U - 1];
    float r1 = out[O_NEI + E + U - 1];
    out[O_NEI + p]     = r0;
    out[O_NEI + E + p] = r1;
}

// edge_index passthrough — LAST kernel; overwrites all scratch in [23M,29M)
__global__ void k_pass(const void* __restrict__ ei, const int* __restrict__ flag,
                       float* __restrict__ out) {
    int e = blockIdx.x * blockDim.x + threadIdx.x;
    if (e >= E) return;
    int mode = *flag;
    out[O_EIP + e]     = (float)load_ei(ei, e, mode);
    out[O_EIP + E + e] = (float)load_ei(ei, E + e, mode);
}

static inline void scan3(float* out, long long in_off, long long out_off, int n,
                         hipStream_t stream) {
    k_scan_part<<<ST / 256, 256, 0, stream>>>(out, in_off, n);
    k_scan1<<<1, 1024, 0, stream>>>(out, S_PT, S_PT2, ST);
    k_scan_out<<<ST / 256, 256, 0, stream>>>(out, in_off, out_off, n);
}

extern "C" void kernel_launch(void* const* d_in, const int* in_sizes, int n_in,
                              void* d_out, int out_size, void* d_ws, size_t ws_size,
                              hipStream_t stream) {
    const float* x     = (const float*)d_in[0];
    const void*  ei    = d_in[1];
    const float* xpos  = (const float*)d_in[2];
    const float* iat   = (const float*)d_in[3];
    const float* batch = (const float*)d_in[4];
    const int*   pool  = (const int*)d_in[5];
    float* out = (float*)d_out;
    int* flag = (int*)d_ws;

    int eblocks = (int)((E + 4095) / 4096);   // 733

    hipMemsetAsync(out + S_CNT, 0, (size_t)M * 4, stream);
    hipMemsetAsync(out + S_CBN, 0, (size_t)NC * 4, stream);

    k_detect<<<1, 64, 0, stream>>>(ei, flag);
    k_rows<<<(N + 255) / 256, 256, 0, stream>>>(iat, batch, pool, out);
    scan3(out, S_CNT, S_COF, M, stream);
    k_rowscatter<<<(N + 255) / 256, 256, 0, stream>>>(out);

    long long txm = (long long)M * 64;
    k_xmean<<<(unsigned)((txm + 255) / 256), 256, 0, stream>>>(
        (const float4*)x, xpos, iat, batch, out);

    k_edges2<<<eblocks, 256, 0, stream>>>(ei, flag, out);
    k_scan512<<<1, NC, 0, stream>>>(out, S_CBN, S_CBS, S_CPS);
    k_part<<<eblocks, 512, 0, stream>>>(out);
    k_psort<<<NC, 1024, 0, stream>>>(out);
    k_scan512<<<1, NC, 0, stream>>>(out, S_UCT, S_UOF, -1);
    k_uwrite2<<<NC, 256, 0, stream>>>(out);
    k_fill<<<(unsigned)((E + 255) / 256), 256, 0, stream>>>(out);
    k_pass<<<(unsigned)((E + 255) / 256), 256, 0, stream>>>(ei, flag, out);
}

// Round 10
// 515.155 us; speedup vs baseline: 4.2890x; 1.0890x over previous
//
#include <hip/hip_runtime.h>

namespace {
constexpr int N  = 500000;
constexpr long long E = 3000000;
constexpr int C  = 128;
constexpr int M  = 125000;
constexpr int NP = 5;
constexpr int ST = 65536;       // scan3 partial threads
constexpr int NC = 512;         // coarse buckets (key >> 23)
constexpr int PMAX = 8192;      // partition pad (max expected ~6.8k)

// d_out flat layout (float32), reference return order:
constexpr long long O_XF  = 0;          // new_xfinal      M*C
constexpr long long O_NEI = 16000000;   // new_edge_index  2*E
constexpr long long O_POS = 22000000;   // new_pos         M*2
constexpr long long O_IAT = 22250000;   // indexatttennew  M*5
constexpr long long O_NB  = 22875000;   // new_batch       M
constexpr long long O_EIP = 23000000;   // edge_index      2*E
constexpr long long O_CL  = 29000000;   // cluster         N
constexpr long long O_BAT = 29500000;   // batch           N

// scratch overlays in region B = O_EIP row0 [23M,26M); k_pass (last) is the
// only later writer. All windows time-disjoint.
constexpr long long S_CNT = 23000000;   // counts  M ints
constexpr long long S_CLU = 23130000;   // cluster N ints
constexpr long long S_COF = 23640000;   // coff    M+1 ints
constexpr long long S_RPM = 23770000;   // rpm     N ints (ends 24.27M)
constexpr long long S_PT  = 25320000;   // scan3 partials  ST
constexpr long long S_PT2 = 25390000;   // scan3 partials2 ST+1
constexpr long long S_CBN = 25500000;   // coarse counts NC
constexpr long long S_CBS = 25501000;   // cbase NC+1
constexpr long long S_CPS = 25502000;   // cpos  NC (running reservation)
constexpr long long S_UCT = 25503000;   // ucount NC
constexpr long long S_UOF = 25504000;   // uoff  NC+1
// staged keys (E u32)  = O_NEI row0 [16M,19M), dead after k_part
// bdata (E u32)        = O_EIP row1 [26M,29M), dead after k_uwrite2
}

// mode: 1=int64, 3=float64, 0=int32, 2=float32
__global__ void k_detect(const void* __restrict__ ei, int* __restrict__ flag) {
    if (threadIdx.x != 0 || blockIdx.x != 0) return;
    const unsigned long long* q = (const unsigned long long*)ei;
    unsigned long long hi = 0, lo = 0;
    for (int i = 0; i < 64; ++i) {
        unsigned long long a = q[i];
        unsigned long long b = q[(size_t)E / 2 + i];
        hi |= (a >> 32) | (b >> 32);
        lo |= (a & 0xffffffffULL) | (b & 0xffffffffULL);
    }
    int mode;
    if (hi == 0) mode = 1;
    else if (lo == 0) mode = 3;
    else {
        const int* p = (const int*)ei;
        int ok = 1;
        for (int i = 0; i < 256; ++i) {
            int v0 = p[i], v1 = p[E + i];
            if (v0 < 0 || v0 >= N || v1 < 0 || v1 >= N) ok = 0;
        }
        mode = ok ? 0 : 2;
    }
    *flag = mode;
}

__device__ __forceinline__ int load_ei(const void* ei, long long idx, int mode) {
    long long v;
    if (mode == 1)      v = ((const long long*)ei)[idx];
    else if (mode == 0) v = (long long)((const int*)ei)[idx];
    else if (mode == 3) v = (long long)(((const double*)ei)[idx]);
    else                v = (long long)(((const float*)ei)[idx]);
    if (v < 0 || v >= N) v = 0;
    return (int)v;
}

// int32-wraparound key (JAX x64-disabled), biased: unsigned cmp == signed cmp
__device__ __forceinline__ unsigned make_key(int c0, int c1) {
    unsigned uv = (unsigned)c0 * (unsigned)M + (unsigned)c1;
    return uv ^ 0x80000000u;
}

__global__ void k_rows(const float* __restrict__ iat, const float* __restrict__ batch,
                       const int* __restrict__ pool, float* __restrict__ out) {
    int i = blockIdx.x * blockDim.x + threadIdx.x;
    if (i >= N) return;
    int p = pool[0];
    int c = (int)iat[(long long)i * NP + p];
    ((int*)(out + S_CLU))[i] = c;
    out[O_CL + i] = (float)c;
    out[O_BAT + i] = batch[i];
    atomicAdd((int*)(out + S_CNT) + c, 1);
}

// ---- 3-level exclusive scan for coff (M elements) ----
__global__ void k_scan_part(const float* __restrict__ ob, long long in_off, int n) {
    int t = blockIdx.x * blockDim.x + threadIdx.x;
    const int* in = (const int*)(ob + in_off);
    int* pt = (int*)(ob + S_PT);
    int chunk = (n + ST - 1) / ST;
    int s = t * chunk, e = s + chunk;
    if (s > n) s = n;
    if (e > n) e = n;
    int sum = 0;
    for (int i = s; i < e; ++i) sum += in[i];
    pt[t] = sum;
}

__global__ void k_scan1(const float* __restrict__ ob, long long in_off,
                        long long out_off, int n) {
    const int* in = (const int*)(ob + in_off);
    int* outp = (int*)(ob + out_off);
    __shared__ int sh[1024];
    int tid = threadIdx.x;
    int chunk = (n + 1023) / 1024;
    int start = tid * chunk, end = start + chunk;
    if (start > n) start = n;
    if (end > n) end = n;
    int s = 0;
    for (int i = start; i < end; ++i) s += in[i];
    sh[tid] = s;
    __syncthreads();
    for (int off = 1; off < 1024; off <<= 1) {
        int v = (tid >= off) ? sh[tid - off] : 0;
        __syncthreads();
        sh[tid] += v;
        __syncthreads();
    }
    int run = (tid == 0) ? 0 : sh[tid - 1];
    for (int i = start; i < end; ++i) { outp[i] = run; run += in[i]; }
    if (tid == 1023) outp[n] = sh[1023];
}

__global__ void k_scan_out(const float* __restrict__ ob, long long in_off,
                           long long out_off, int n) {
    int t = blockIdx.x * blockDim.x + threadIdx.x;
    const int* in = (const int*)(ob + in_off);
    int* outp = (int*)(ob + out_off);
    int run = ((const int*)(ob + S_PT2))[t];
    int chunk = (n + ST - 1) / ST;
    int s = t * chunk, e = s + chunk;
    if (s > n) s = n;
    if (e > n) e = n;
    for (int i = s; i < e; ++i) { outp[i] = run; run += in[i]; }
    if (t == ST - 1) outp[n] = run;
}

__global__ void k_rowscatter(float* __restrict__ out) {
    int i = blockIdx.x * blockDim.x + threadIdx.x;
    if (i >= N) return;
    int c = ((const int*)(out + S_CLU))[i];
    int pos = atomicAdd((int*)(out + S_COF) + c, 1);
    ((int*)(out + S_RPM))[pos] = i;
}

// one wave per cluster; rpm chunk pre-loaded (coalesced) + shfl broadcast;
// 4 rows in flight per iteration (16-lane groups × 2 float4 = 32B/lane)
__global__ void k_xmean(const float4* __restrict__ x4, float* __restrict__ out) {
    long long t = (long long)blockIdx.x * blockDim.x + threadIdx.x;
    int wid = (int)(t >> 6);
    int lane = threadIdx.x & 63;
    if (wid >= M) return;
    const int* coff = (const int*)(out + S_COF);
    int start = (wid == 0) ? 0 : coff[wid - 1];
    int end = coff[wid];
    int cnt = end - start;
    float fcnt = (float)cnt;
    if (fcnt < 1.0f) fcnt = 1.0f;
    const int* rpm = (const int*)(out + S_RPM);
    int g = lane >> 4;        // row group 0..3
    int sub = lane & 15;      // 2-float4 column slot
    float4 a0 = make_float4(0.f, 0.f, 0.f, 0.f);
    float4 a1 = make_float4(0.f, 0.f, 0.f, 0.f);
    for (int cb = 0; cb < cnt; cb += 64) {
        int rem = cnt - cb;
        if (rem > 64) rem = 64;
        int rl = (lane < rem) ? rpm[start + cb + lane] : 0;
        for (int r = g; r < rem; r += 4) {
            int row = __shfl(rl, r, 64);
            long long b = (long long)row * 32 + sub * 2;
            float4 v0 = x4[b];
            float4 v1 = x4[b + 1];
            a0.x += v0.x; a0.y += v0.y; a0.z += v0.z; a0.w += v0.w;
            a1.x += v1.x; a1.y += v1.y; a1.z += v1.z; a1.w += v1.w;
        }
    }
    a0.x += __shfl_xor(a0.x, 16, 64); a0.y += __shfl_xor(a0.y, 16, 64);
    a0.z += __shfl_xor(a0.z, 16, 64); a0.w += __shfl_xor(a0.w, 16, 64);
    a1.x += __shfl_xor(a1.x, 16, 64); a1.y += __shfl_xor(a1.y, 16, 64);
    a1.z += __shfl_xor(a1.z, 16, 64); a1.w += __shfl_xor(a1.w, 16, 64);
    a0.x += __shfl_xor(a0.x, 32, 64); a0.y += __shfl_xor(a0.y, 32, 64);
    a0.z += __shfl_xor(a0.z, 32, 64); a0.w += __shfl_xor(a0.w, 32, 64);
    a1.x += __shfl_xor(a1.x, 32, 64); a1.y += __shfl_xor(a1.y, 32, 64);
    a1.z += __shfl_xor(a1.z, 32, 64); a1.w += __shfl_xor(a1.w, 32, 64);
    if (lane < 16) {
        float4 o0, o1;
        o0.x = a0.x / fcnt; o0.y = a0.y / fcnt; o0.z = a0.z / fcnt; o0.w = a0.w / fcnt;
        o1.x = a1.x / fcnt; o1.y = a1.y / fcnt; o1.z = a1.z / fcnt; o1.w = a1.w / fcnt;
        long long b = (long long)wid * 32 + sub * 2;
        ((float4*)(out + O_XF))[b]     = o0;
        ((float4*)(out + O_XF))[b + 1] = o1;
    }
}

// small-column means: one thread per (cluster, col); xpos/iat/batch are
// L2/L3-resident (16 MB total)
__global__ void k_smallmean(const float* __restrict__ xpos, const float* __restrict__ iat,
                            const float* __restrict__ batch, float* __restrict__ out) {
    int t = blockIdx.x * blockDim.x + threadIdx.x;
    if (t >= M * 8) return;
    int m = t >> 3;
    int lc = t & 7;
    const int* coff = (const int*)(out + S_COF);
    int start = (m == 0) ? 0 : coff[m - 1];
    int end = coff[m];
    float cnt = (float)(end - start);
    if (cnt < 1.0f) cnt = 1.0f;
    const int* rpm = (const int*)(out + S_RPM);
    float s = 0.0f;
    for (int r = start; r < end; ++r) {
        int row = rpm[r];
        float v;
        if (lc < 2)      v = xpos[(long long)row * 2 + lc];
        else if (lc < 7) v = iat[(long long)row * NP + (lc - 2)];
        else             v = batch[row];
        s += v;
    }
    float mres = s / cnt;
    if (lc >= 2) mres = truncf(mres);
    if (lc < 2)      out[O_POS + (long long)m * 2 + lc] = mres;
    else if (lc < 7) out[O_IAT + (long long)m * NP + (lc - 2)] = mres;
    else             out[O_NB + m] = mres;
}

// stage keys + LDS-aggregated coarse histogram (512 buckets, top-9 bits)
__global__ __launch_bounds__(256) void k_edges2(const void* __restrict__ ei,
                                                const int* __restrict__ flag,
                                                float* __restrict__ out) {
    __shared__ int h[NC];
    int tid = threadIdx.x;
    long long cb = (long long)blockIdx.x * 4096;
    for (int s = tid; s < NC; s += 256) h[s] = 0;
    __syncthreads();
    int mode = *flag;
    const int* cluster = (const int*)(out + S_CLU);
    unsigned* stage = (unsigned*)(out + O_NEI);
    for (int s = 0; s < 16; ++s) {
        long long i = cb + s * 256 + tid;
        if (i < E) {
            int c0 = cluster[load_ei(ei, i, mode)];
            int c1 = cluster[load_ei(ei, E + i, mode)];
            unsigned key = make_key(c0, c1);
            stage[i] = key;
            atomicAdd(&h[key >> 23], 1);
        }
    }
    __syncthreads();
    for (int s = tid; s < NC; s += 256) {
        int v = h[s];
        if (v) atomicAdd((int*)(out + S_CBN) + s, v);
    }
}

// single-block exclusive scan of NC=512; also optionally seeds cpos
__global__ void k_scan512(float* __restrict__ out, long long in_off,
                          long long out_off, long long pos_off) {
    __shared__ int sh[NC];
    int tid = threadIdx.x;
    const int* in = (const int*)(out + in_off);
    int* o = (int*)(out + out_off);
    int v0 = in[tid];
    sh[tid] = v0;
    __syncthreads();
    for (int off = 1; off < NC; off <<= 1) {
        int v = (tid >= off) ? sh[tid - off] : 0;
        __syncthreads();
        sh[tid] += v;
        __syncthreads();
    }
    int excl = sh[tid] - v0;
    o[tid] = excl;
    if (pos_off >= 0) ((int*)(out + pos_off))[tid] = excl;
    if (tid == NC - 1) o[NC] = sh[NC - 1];
}

// LDS-aggregated partition: group 4096 staged keys by coarse bucket, reserve
// global runs (1 atomic per block-bucket), write contiguous runs into bdata
__global__ __launch_bounds__(512) void k_part(float* __restrict__ out) {
    __shared__ int h[NC], h2[NC], lb[NC], gb[NC];
    __shared__ unsigned g[4096];
    __shared__ int d[4096];
    int tid = threadIdx.x;
    long long cb = (long long)blockIdx.x * 4096;
    const unsigned* stage = (const unsigned*)(out + O_NEI);
    unsigned* bdata = (unsigned*)(out + O_EIP + E);
    if (tid < NC) { h[tid] = 0; h2[tid] = 0; }
    __syncthreads();
    unsigned keys[8];
    for (int s = 0; s < 8; ++s) {
        long long i = cb + s * 512 + tid;
        if (i < E) {
            unsigned key = stage[i];
            keys[s] = key;
            atomicAdd(&h[key >> 23], 1);
        }
    }
    __syncthreads();
    if (tid < NC) lb[tid] = h[tid];
    __syncthreads();
    for (int off = 1; off < NC; off <<= 1) {
        int v = (tid < NC && tid >= off) ? lb[tid - off] : 0;
        __syncthreads();
        if (tid < NC) lb[tid] += v;
        __syncthreads();
    }
    if (tid < NC) {
        int excl = lb[tid] - h[tid];
        gb[tid] = atomicAdd((int*)(out + S_CPS) + tid, h[tid]);
        lb[tid] = excl;
    }
    __syncthreads();
    for (int s = 0; s < 8; ++s) {
        long long i = cb + s * 512 + tid;
        if (i < E) {
            unsigned key = keys[s];
            int b = key >> 23;
            int r = atomicAdd(&h2[b], 1);
            int slot = lb[b] + r;
            g[slot] = key;
            d[slot] = gb[b] + r;
        }
    }
    __syncthreads();
    int tot = (int)((E - cb < 4096) ? (E - cb) : 4096);
    for (int s = 0; s < 8; ++s) {
        int slot = tid + s * 512;
        if (slot < tot) bdata[d[slot]] = g[slot];
    }
}

// per-partition in-LDS bitonic sort + dedupe-compact, write back in place
__global__ __launch_bounds__(1024) void k_psort(float* __restrict__ out) {
    __shared__ unsigned sk[PMAX];
    __shared__ int ssc[1024];
    int p = blockIdx.x;
    int tid = threadIdx.x;
    const int* cbase = (const int*)(out + S_CBS);
    int base = cbase[p];
    int n = cbase[p + 1] - base;
    if (n > PMAX) n = PMAX;   // unreachable guard
    unsigned* bdata = (unsigned*)(out + O_EIP + E);
    for (int i = tid; i < PMAX; i += 1024)
        sk[i] = (i < n) ? bdata[base + i] : 0xFFFFFFFFu;
    __syncthreads();
    for (int k = 2; k <= PMAX; k <<= 1) {
        for (int j = k >> 1; j > 0; j >>= 1) {
            for (int i = tid; i < PMAX; i += 1024) {
                int ixj = i ^ j;
                if (ixj > i) {
                    unsigned a = sk[i], b = sk[ixj];
                    bool up = ((i & k) == 0);
                    if ((a > b) == up) { sk[i] = b; sk[ixj] = a; }
                }
            }
            __syncthreads();
        }
    }
    int c = 0;
    for (int s = 0; s < PMAX / 1024; ++s) {
        int i = tid * (PMAX / 1024) + s;
        bool v = (i < n) && (i == 0 || sk[i] != sk[i - 1]);
        c += v ? 1 : 0;
    }
    ssc[tid] = c;
    __syncthreads();
    for (int off = 1; off < 1024; off <<= 1) {
        int v = (tid >= off) ? ssc[tid - off] : 0;
        __syncthreads();
        ssc[tid] += v;
        __syncthreads();
    }
    int pos = ssc[tid] - c;
    for (int s = 0; s < PMAX / 1024; ++s) {
        int i = tid * (PMAX / 1024) + s;
        bool v = (i < n) && (i == 0 || sk[i] != sk[i - 1]);
        if (v) bdata[base + pos++] = sk[i];
    }
    if (tid == 1023) ((int*)(out + S_UCT))[p] = ssc[1023];
}

// copy each partition's sorted unique keys to final position, decoded
__global__ __launch_bounds__(256) void k_uwrite2(float* __restrict__ out) {
    int p = blockIdx.x;
    int tid = threadIdx.x;
    int base = ((const int*)(out + S_CBS))[p];
    int u    = ((const int*)(out + S_UCT))[p];
    long long dst = ((const int*)(out + S_UOF))[p];
    const unsigned* bdata = (const unsigned*)(out + O_EIP + E);
    for (int i = tid; i < u; i += 256) {
        unsigned v = bdata[base + i];
        long long k = (long long)(int)(v ^ 0x80000000u);
        long long r = k % M; if (r < 0) r += M;
        long long q = (k - r) / M;
        out[O_NEI + dst + i]     = (float)q;
        out[O_NEI + E + dst + i] = (float)r;
    }
}

// tail fill = last sorted unique pair (== keys.max())
__global__ void k_fill(float* __restrict__ out) {
    int p = blockIdx.x * blockDim.x + threadIdx.x;
    if (p >= E) return;
    int U = ((const int*)(out + S_UOF))[NC];
    if (p < U) return;
    float r0 = out[O_NEI + U - 1];
    float r1 = out[O_NEI + E + U - 1];
    out[O_NEI + p]     = r0;
    out[O_NEI + E + p] = r1;
}

// edge_index passthrough — LAST kernel; overwrites all scratch in [23M,29M)
__global__ void k_pass(const void* __restrict__ ei, const int* __restrict__ flag,
                       float* __restrict__ out) {
    int e = blockIdx.x * blockDim.x + threadIdx.x;
    if (e >= E) return;
    int mode = *flag;
    out[O_EIP + e]     = (float)load_ei(ei, e, mode);
    out[O_EIP + E + e] = (float)load_ei(ei, E + e, mode);
}

static inline void scan3(float* out, long long in_off, long long out_off, int n,
                         hipStream_t stream) {
    k_scan_part<<<ST / 256, 256, 0, stream>>>(out, in_off, n);
    k_scan1<<<1, 1024, 0, stream>>>(out, S_PT, S_PT2, ST);
    k_scan_out<<<ST / 256, 256, 0, stream>>>(out, in_off, out_off, n);
}

extern "C" void kernel_launch(void* const* d_in, const int* in_sizes, int n_in,
                              void* d_out, int out_size, void* d_ws, size_t ws_size,
                              hipStream_t stream) {
    const float* x     = (const float*)d_in[0];
    const void*  ei    = d_in[1];
    const float* xpos  = (const float*)d_in[2];
    const float* iat   = (const float*)d_in[3];
    const float* batch = (const float*)d_in[4];
    const int*   pool  = (const int*)d_in[5];
    float* out = (float*)d_out;
    int* flag = (int*)d_ws;

    int eblocks = (int)((E + 4095) / 4096);   // 733

    hipMemsetAsync(out + S_CNT, 0, (size_t)M * 4, stream);
    hipMemsetAsync(out + S_CBN, 0, (size_t)NC * 4, stream);

    k_detect<<<1, 64, 0, stream>>>(ei, flag);
    k_rows<<<(N + 255) / 256, 256, 0, stream>>>(iat, batch, pool, out);
    scan3(out, S_CNT, S_COF, M, stream);
    k_rowscatter<<<(N + 255) / 256, 256, 0, stream>>>(out);

    long long txm = (long long)M * 64;
    k_xmean<<<(unsigned)((txm + 255) / 256), 256, 0, stream>>>((const float4*)x, out);
    k_smallmean<<<(M * 8 + 255) / 256, 256, 0, stream>>>(xpos, iat, batch, out);

    k_edges2<<<eblocks, 256, 0, stream>>>(ei, flag, out);
    k_scan512<<<1, NC, 0, stream>>>(out, S_CBN, S_CBS, S_CPS);
    k_part<<<eblocks, 512, 0, stream>>>(out);
    k_psort<<<NC, 1024, 0, stream>>>(out);
    k_scan512<<<1, NC, 0, stream>>>(out, S_UCT, S_UOF, -1);
    k_uwrite2<<<NC, 256, 0, stream>>>(out);
    k_fill<<<(unsigned)((E + 255) / 256), 256, 0, stream>>>(out);
    k_pass<<<(unsigned)((E + 255) / 256), 256, 0, stream>>>(ei, flag, out);
}

// Round 11
// 391.412 us; speedup vs baseline: 5.6450x; 1.3161x over previous
//
#include <hip/hip_runtime.h>

namespace {
constexpr int N  = 500000;
constexpr long long E = 3000000;
constexpr int C  = 128;
constexpr int M  = 125000;
constexpr int NP = 5;
constexpr int ST = 65536;       // scan3 partial threads
constexpr int NC = 512;         // coarse buckets (key >> 23)
constexpr int PMAX = 8192;      // partition pad (max expected ~6.8k)
constexpr int NSB = 2048;       // sub-buckets per partition ((key>>12)&2047)

// d_out flat layout (float32), reference return order:
constexpr long long O_XF  = 0;          // new_xfinal      M*C
constexpr long long O_NEI = 16000000;   // new_edge_index  2*E
constexpr long long O_POS = 22000000;   // new_pos         M*2
constexpr long long O_IAT = 22250000;   // indexatttennew  M*5
constexpr long long O_NB  = 22875000;   // new_batch       M
constexpr long long O_EIP = 23000000;   // edge_index      2*E
constexpr long long O_CL  = 29000000;   // cluster         N
constexpr long long O_BAT = 29500000;   // batch           N

// scratch overlays in region B = O_EIP row0 [23M,26M); k_pass (last) is the
// only later writer. All windows time-disjoint.
constexpr long long S_CNT = 23000000;   // counts  M ints
constexpr long long S_CLU = 23130000;   // cluster N ints
constexpr long long S_COF = 23640000;   // coff    M+1 ints
constexpr long long S_RPM = 23770000;   // rpm     N ints (ends 24.27M)
constexpr long long S_PT  = 25320000;   // scan3 partials  ST
constexpr long long S_PT2 = 25390000;   // scan3 partials2 ST+1
constexpr long long S_CBN = 25500000;   // coarse counts NC
constexpr long long S_CBS = 25501000;   // cbase NC+1
constexpr long long S_CPS = 25502000;   // cpos  NC (running reservation)
constexpr long long S_UCT = 25503000;   // ucount NC
constexpr long long S_UOF = 25504000;   // uoff  NC+1
// staged keys (E u32)  = O_NEI row0 [16M,19M), dead after k_part
// bdata (E u32)        = O_EIP row1 [26M,29M), dead after k_uwrite2
}

// mode: 1=int64, 3=float64, 0=int32, 2=float32
__global__ void k_detect(const void* __restrict__ ei, int* __restrict__ flag) {
    if (threadIdx.x != 0 || blockIdx.x != 0) return;
    const unsigned long long* q = (const unsigned long long*)ei;
    unsigned long long hi = 0, lo = 0;
    for (int i = 0; i < 64; ++i) {
        unsigned long long a = q[i];
        unsigned long long b = q[(size_t)E / 2 + i];
        hi |= (a >> 32) | (b >> 32);
        lo |= (a & 0xffffffffULL) | (b & 0xffffffffULL);
    }
    int mode;
    if (hi == 0) mode = 1;
    else if (lo == 0) mode = 3;
    else {
        const int* p = (const int*)ei;
        int ok = 1;
        for (int i = 0; i < 256; ++i) {
            int v0 = p[i], v1 = p[E + i];
            if (v0 < 0 || v0 >= N || v1 < 0 || v1 >= N) ok = 0;
        }
        mode = ok ? 0 : 2;
    }
    *flag = mode;
}

__device__ __forceinline__ int load_ei(const void* ei, long long idx, int mode) {
    long long v;
    if (mode == 1)      v = ((const long long*)ei)[idx];
    else if (mode == 0) v = (long long)((const int*)ei)[idx];
    else if (mode == 3) v = (long long)(((const double*)ei)[idx]);
    else                v = (long long)(((const float*)ei)[idx]);
    if (v < 0 || v >= N) v = 0;
    return (int)v;
}

// int32-wraparound key (JAX x64-disabled), biased: unsigned cmp == signed cmp
__device__ __forceinline__ unsigned make_key(int c0, int c1) {
    unsigned uv = (unsigned)c0 * (unsigned)M + (unsigned)c1;
    return uv ^ 0x80000000u;
}

__global__ void k_rows(const float* __restrict__ iat, const float* __restrict__ batch,
                       const int* __restrict__ pool, float* __restrict__ out) {
    int i = blockIdx.x * blockDim.x + threadIdx.x;
    if (i >= N) return;
    int p = pool[0];
    int c = (int)iat[(long long)i * NP + p];
    ((int*)(out + S_CLU))[i] = c;
    out[O_CL + i] = (float)c;
    out[O_BAT + i] = batch[i];
    atomicAdd((int*)(out + S_CNT) + c, 1);
}

// ---- 3-level exclusive scan for coff (M elements) ----
__global__ void k_scan_part(const float* __restrict__ ob, long long in_off, int n) {
    int t = blockIdx.x * blockDim.x + threadIdx.x;
    const int* in = (const int*)(ob + in_off);
    int* pt = (int*)(ob + S_PT);
    int chunk = (n + ST - 1) / ST;
    int s = t * chunk, e = s + chunk;
    if (s > n) s = n;
    if (e > n) e = n;
    int sum = 0;
    for (int i = s; i < e; ++i) sum += in[i];
    pt[t] = sum;
}

__global__ void k_scan1(const float* __restrict__ ob, long long in_off,
                        long long out_off, int n) {
    const int* in = (const int*)(ob + in_off);
    int* outp = (int*)(ob + out_off);
    __shared__ int sh[1024];
    int tid = threadIdx.x;
    int chunk = (n + 1023) / 1024;
    int start = tid * chunk, end = start + chunk;
    if (start > n) start = n;
    if (end > n) end = n;
    int s = 0;
    for (int i = start; i < end; ++i) s += in[i];
    sh[tid] = s;
    __syncthreads();
    for (int off = 1; off < 1024; off <<= 1) {
        int v = (tid >= off) ? sh[tid - off] : 0;
        __syncthreads();
        sh[tid] += v;
        __syncthreads();
    }
    int run = (tid == 0) ? 0 : sh[tid - 1];
    for (int i = start; i < end; ++i) { outp[i] = run; run += in[i]; }
    if (tid == 1023) outp[n] = sh[1023];
}

__global__ void k_scan_out(const float* __restrict__ ob, long long in_off,
                           long long out_off, int n) {
    int t = blockIdx.x * blockDim.x + threadIdx.x;
    const int* in = (const int*)(ob + in_off);
    int* outp = (int*)(ob + out_off);
    int run = ((const int*)(ob + S_PT2))[t];
    int chunk = (n + ST - 1) / ST;
    int s = t * chunk, e = s + chunk;
    if (s > n) s = n;
    if (e > n) e = n;
    for (int i = s; i < e; ++i) { outp[i] = run; run += in[i]; }
    if (t == ST - 1) outp[n] = run;
}

__global__ void k_rowscatter(float* __restrict__ out) {
    int i = blockIdx.x * blockDim.x + threadIdx.x;
    if (i >= N) return;
    int c = ((const int*)(out + S_CLU))[i];
    int pos = atomicAdd((int*)(out + S_COF) + c, 1);
    ((int*)(out + S_RPM))[pos] = i;
}

// one wave per cluster; rpm chunk pre-loaded (coalesced) + shfl broadcast;
// 4 rows in flight per iteration (16-lane groups × 2 float4 = 32B/lane)
__global__ void k_xmean(const float4* __restrict__ x4, float* __restrict__ out) {
    long long t = (long long)blockIdx.x * blockDim.x + threadIdx.x;
    int wid = (int)(t >> 6);
    int lane = threadIdx.x & 63;
    if (wid >= M) return;
    const int* coff = (const int*)(out + S_COF);
    int start = (wid == 0) ? 0 : coff[wid - 1];
    int end = coff[wid];
    int cnt = end - start;
    float fcnt = (float)cnt;
    if (fcnt < 1.0f) fcnt = 1.0f;
    const int* rpm = (const int*)(out + S_RPM);
    int g = lane >> 4;        // row group 0..3
    int sub = lane & 15;      // 2-float4 column slot
    float4 a0 = make_float4(0.f, 0.f, 0.f, 0.f);
    float4 a1 = make_float4(0.f, 0.f, 0.f, 0.f);
    for (int cb = 0; cb < cnt; cb += 64) {
        int rem = cnt - cb;
        if (rem > 64) rem = 64;
        int rl = (lane < rem) ? rpm[start + cb + lane] : 0;
        for (int r = g; r < rem; r += 4) {
            int row = __shfl(rl, r, 64);
            long long b = (long long)row * 32 + sub * 2;
            float4 v0 = x4[b];
            float4 v1 = x4[b + 1];
            a0.x += v0.x; a0.y += v0.y; a0.z += v0.z; a0.w += v0.w;
            a1.x += v1.x; a1.y += v1.y; a1.z += v1.z; a1.w += v1.w;
        }
    }
    a0.x += __shfl_xor(a0.x, 16, 64); a0.y += __shfl_xor(a0.y, 16, 64);
    a0.z += __shfl_xor(a0.z, 16, 64); a0.w += __shfl_xor(a0.w, 16, 64);
    a1.x += __shfl_xor(a1.x, 16, 64); a1.y += __shfl_xor(a1.y, 16, 64);
    a1.z += __shfl_xor(a1.z, 16, 64); a1.w += __shfl_xor(a1.w, 16, 64);
    a0.x += __shfl_xor(a0.x, 32, 64); a0.y += __shfl_xor(a0.y, 32, 64);
    a0.z += __shfl_xor(a0.z, 32, 64); a0.w += __shfl_xor(a0.w, 32, 64);
    a1.x += __shfl_xor(a1.x, 32, 64); a1.y += __shfl_xor(a1.y, 32, 64);
    a1.z += __shfl_xor(a1.z, 32, 64); a1.w += __shfl_xor(a1.w, 32, 64);
    if (lane < 16) {
        float4 o0, o1;
        o0.x = a0.x / fcnt; o0.y = a0.y / fcnt; o0.z = a0.z / fcnt; o0.w = a0.w / fcnt;
        o1.x = a1.x / fcnt; o1.y = a1.y / fcnt; o1.z = a1.z / fcnt; o1.w = a1.w / fcnt;
        long long b = (long long)wid * 32 + sub * 2;
        ((float4*)(out + O_XF))[b]     = o0;
        ((float4*)(out + O_XF))[b + 1] = o1;
    }
}

// small-column means: one thread per (cluster, col); xpos/iat/batch are
// L2/L3-resident (16 MB total)
__global__ void k_smallmean(const float* __restrict__ xpos, const float* __restrict__ iat,
                            const float* __restrict__ batch, float* __restrict__ out) {
    int t = blockIdx.x * blockDim.x + threadIdx.x;
    if (t >= M * 8) return;
    int m = t >> 3;
    int lc = t & 7;
    const int* coff = (const int*)(out + S_COF);
    int start = (m == 0) ? 0 : coff[m - 1];
    int end = coff[m];
    float cnt = (float)(end - start);
    if (cnt < 1.0f) cnt = 1.0f;
    const int* rpm = (const int*)(out + S_RPM);
    float s = 0.0f;
    for (int r = start; r < end; ++r) {
        int row = rpm[r];
        float v;
        if (lc < 2)      v = xpos[(long long)row * 2 + lc];
        else if (lc < 7) v = iat[(long long)row * NP + (lc - 2)];
        else             v = batch[row];
        s += v;
    }
    float mres = s / cnt;
    if (lc >= 2) mres = truncf(mres);
    if (lc < 2)      out[O_POS + (long long)m * 2 + lc] = mres;
    else if (lc < 7) out[O_IAT + (long long)m * NP + (lc - 2)] = mres;
    else             out[O_NB + m] = mres;
}

// stage keys + LDS-aggregated coarse histogram (512 buckets, top-9 bits)
__global__ __launch_bounds__(256) void k_edges2(const void* __restrict__ ei,
                                                const int* __restrict__ flag,
                                                float* __restrict__ out) {
    __shared__ int h[NC];
    int tid = threadIdx.x;
    long long cb = (long long)blockIdx.x * 4096;
    for (int s = tid; s < NC; s += 256) h[s] = 0;
    __syncthreads();
    int mode = *flag;
    const int* cluster = (const int*)(out + S_CLU);
    unsigned* stage = (unsigned*)(out + O_NEI);
    for (int s = 0; s < 16; ++s) {
        long long i = cb + s * 256 + tid;
        if (i < E) {
            int c0 = cluster[load_ei(ei, i, mode)];
            int c1 = cluster[load_ei(ei, E + i, mode)];
            unsigned key = make_key(c0, c1);
            stage[i] = key;
            atomicAdd(&h[key >> 23], 1);
        }
    }
    __syncthreads();
    for (int s = tid; s < NC; s += 256) {
        int v = h[s];
        if (v) atomicAdd((int*)(out + S_CBN) + s, v);
    }
}

// single-block exclusive scan of NC=512; also optionally seeds cpos
__global__ void k_scan512(float* __restrict__ out, long long in_off,
                          long long out_off, long long pos_off) {
    __shared__ int sh[NC];
    int tid = threadIdx.x;
    const int* in = (const int*)(out + in_off);
    int* o = (int*)(out + out_off);
    int v0 = in[tid];
    sh[tid] = v0;
    __syncthreads();
    for (int off = 1; off < NC; off <<= 1) {
        int v = (tid >= off) ? sh[tid - off] : 0;
        __syncthreads();
        sh[tid] += v;
        __syncthreads();
    }
    int excl = sh[tid] - v0;
    o[tid] = excl;
    if (pos_off >= 0) ((int*)(out + pos_off))[tid] = excl;
    if (tid == NC - 1) o[NC] = sh[NC - 1];
}

// LDS-aggregated partition: group 4096 staged keys by coarse bucket, reserve
// global runs (1 atomic per block-bucket), write contiguous runs into bdata
__global__ __launch_bounds__(512) void k_part(float* __restrict__ out) {
    __shared__ int h[NC], h2[NC], lb[NC], gb[NC];
    __shared__ unsigned g[4096];
    __shared__ int d[4096];
    int tid = threadIdx.x;
    long long cb = (long long)blockIdx.x * 4096;
    const unsigned* stage = (const unsigned*)(out + O_NEI);
    unsigned* bdata = (unsigned*)(out + O_EIP + E);
    if (tid < NC) { h[tid] = 0; h2[tid] = 0; }
    __syncthreads();
    unsigned keys[8];
    for (int s = 0; s < 8; ++s) {
        long long i = cb + s * 512 + tid;
        if (i < E) {
            unsigned key = stage[i];
            keys[s] = key;
            atomicAdd(&h[key >> 23], 1);
        }
    }
    __syncthreads();
    if (tid < NC) lb[tid] = h[tid];
    __syncthreads();
    for (int off = 1; off < NC; off <<= 1) {
        int v = (tid < NC && tid >= off) ? lb[tid - off] : 0;
        __syncthreads();
        if (tid < NC) lb[tid] += v;
        __syncthreads();
    }
    if (tid < NC) {
        int excl = lb[tid] - h[tid];
        gb[tid] = atomicAdd((int*)(out + S_CPS) + tid, h[tid]);
        lb[tid] = excl;
    }
    __syncthreads();
    for (int s = 0; s < 8; ++s) {
        long long i = cb + s * 512 + tid;
        if (i < E) {
            unsigned key = keys[s];
            int b = key >> 23;
            int r = atomicAdd(&h2[b], 1);
            int slot = lb[b] + r;
            g[slot] = key;
            d[slot] = gb[b] + r;
        }
    }
    __syncthreads();
    int tot = (int)((E - cb < 4096) ? (E - cb) : 4096);
    for (int s = 0; s < 8; ++s) {
        int slot = tid + s * 512;
        if (slot < tot) bdata[d[slot]] = g[slot];
    }
}

// per-partition sort via MSD sub-bucketing (keys share top 9 bits):
// scatter by bits 22..12 into 2048 LDS sub-buckets (globally ordered), then
// per-thread insertion sort of avg-2.9-key sub-buckets => fully sorted; then
// dedupe-compact, write back in place.
__global__ __launch_bounds__(1024) void k_psort(float* __restrict__ out) {
    __shared__ unsigned sk2[PMAX];
    __shared__ int hist[NSB];     // exclusive-start, then running end
    __shared__ int hstart[NSB];   // fixed starts
    __shared__ int ssc[1024];
    int p = blockIdx.x;
    int tid = threadIdx.x;
    const int* cbase = (const int*)(out + S_CBS);
    int base = cbase[p];
    int n = cbase[p + 1] - base;
    if (n > PMAX) n = PMAX;   // unreachable guard
    unsigned* bdata = (unsigned*)(out + O_EIP + E);
    for (int i = tid; i < NSB; i += 1024) hist[i] = 0;
    __syncthreads();
    for (int i = tid; i < n; i += 1024)
        atomicAdd(&hist[(bdata[base + i] >> 12) & (NSB - 1)], 1);
    __syncthreads();
    // exclusive scan of 2048 (2 elems/thread)
    int h0 = hist[2 * tid], h1 = hist[2 * tid + 1];
    ssc[tid] = h0 + h1;
    __syncthreads();
    for (int off = 1; off < 1024; off <<= 1) {
        int v = (tid >= off) ? ssc[tid - off] : 0;
        __syncthreads();
        ssc[tid] += v;
        __syncthreads();
    }
    int excl = ssc[tid] - (h0 + h1);
    hstart[2 * tid] = excl;      hstart[2 * tid + 1] = excl + h0;
    __syncthreads();
    hist[2 * tid] = excl;        hist[2 * tid + 1] = excl + h0;  // running pos
    __syncthreads();
    // scatter into sub-buckets (arbitrary order within bucket)
    for (int i = tid; i < n; i += 1024) {
        unsigned k = bdata[base + i];
        int b = (k >> 12) & (NSB - 1);
        int r = atomicAdd(&hist[b], 1);
        sk2[r] = k;
    }
    __syncthreads();
    // per-thread insertion sort of 2 sub-buckets (hist[b] is now bucket end)
    for (int bb = 0; bb < 2; ++bb) {
        int b = 2 * tid + bb;
        int s = hstart[b];
        int e = hist[b];
        for (int i = s + 1; i < e; ++i) {
            unsigned v = sk2[i];
            int j = i - 1;
            while (j >= s && sk2[j] > v) { sk2[j + 1] = sk2[j]; --j; }
            sk2[j + 1] = v;
        }
    }
    __syncthreads();
    // dedup + compact (sk2[0..n) fully sorted)
    int chunk = (n + 1023) / 1024;
    int cs = tid * chunk, ce = cs + chunk;
    if (cs > n) cs = n;
    if (ce > n) ce = n;
    int c = 0;
    for (int i = cs; i < ce; ++i)
        if (i == 0 || sk2[i] != sk2[i - 1]) ++c;
    ssc[tid] = c;
    __syncthreads();
    for (int off = 1; off < 1024; off <<= 1) {
        int v = (tid >= off) ? ssc[tid - off] : 0;
        __syncthreads();
        ssc[tid] += v;
        __syncthreads();
    }
    int pos = ssc[tid] - c;
    for (int i = cs; i < ce; ++i)
        if (i == 0 || sk2[i] != sk2[i - 1]) bdata[base + pos++] = sk2[i];
    if (tid == 1023) ((int*)(out + S_UCT))[p] = ssc[1023];
}

// copy each partition's sorted unique keys to final position, decoded
__global__ __launch_bounds__(256) void k_uwrite2(float* __restrict__ out) {
    int p = blockIdx.x;
    int tid = threadIdx.x;
    int base = ((const int*)(out + S_CBS))[p];
    int u    = ((const int*)(out + S_UCT))[p];
    long long dst = ((const int*)(out + S_UOF))[p];
    const unsigned* bdata = (const unsigned*)(out + O_EIP + E);
    for (int i = tid; i < u; i += 256) {
        unsigned v = bdata[base + i];
        long long k = (long long)(int)(v ^ 0x80000000u);
        long long r = k % M; if (r < 0) r += M;
        long long q = (k - r) / M;
        out[O_NEI + dst + i]     = (float)q;
        out[O_NEI + E + dst + i] = (float)r;
    }
}

// tail fill = last sorted unique pair (== keys.max())
__global__ void k_fill(float* __restrict__ out) {
    int p = blockIdx.x * blockDim.x + threadIdx.x;
    if (p >= E) return;
    int U = ((const int*)(out + S_UOF))[NC];
    if (p < U) return;
    float r0 = out[O_NEI + U - 1];
    float r1 = out[O_NEI + E + U - 1];
    out[O_NEI + p]     = r0;
    out[O_NEI + E + p] = r1;
}

// edge_index passthrough — LAST kernel; overwrites all scratch in [23M,29M)
__global__ void k_pass(const void* __restrict__ ei, const int* __restrict__ flag,
                       float* __restrict__ out) {
    int e = blockIdx.x * blockDim.x + threadIdx.x;
    if (e >= E) return;
    int mode = *flag;
    out[O_EIP + e]     = (float)load_ei(ei, e, mode);
    out[O_EIP + E + e] = (float)load_ei(ei, E + e, mode);
}

static inline void scan3(float* out, long long in_off, long long out_off, int n,
                         hipStream_t stream) {
    k_scan_part<<<ST / 256, 256, 0, stream>>>(out, in_off, n);
    k_scan1<<<1, 1024, 0, stream>>>(out, S_PT, S_PT2, ST);
    k_scan_out<<<ST / 256, 256, 0, stream>>>(out, in_off, out_off, n);
}

extern "C" void kernel_launch(void* const* d_in, const int* in_sizes, int n_in,
                              void* d_out, int out_size, void* d_ws, size_t ws_size,
                              hipStream_t stream) {
    const float* x     = (const float*)d_in[0];
    const void*  ei    = d_in[1];
    const float* xpos  = (const float*)d_in[2];
    const float* iat   = (const float*)d_in[3];
    const float* batch = (const float*)d_in[4];
    const int*   pool  = (const int*)d_in[5];
    float* out = (float*)d_out;
    int* flag = (int*)d_ws;

    int eblocks = (int)((E + 4095) / 4096);   // 733

    hipMemsetAsync(out + S_CNT, 0, (size_t)M * 4, stream);
    hipMemsetAsync(out + S_CBN, 0, (size_t)NC * 4, stream);

    k_detect<<<1, 64, 0, stream>>>(ei, flag);
    k_rows<<<(N + 255) / 256, 256, 0, stream>>>(iat, batch, pool, out);
    scan3(out, S_CNT, S_COF, M, stream);
    k_rowscatter<<<(N + 255) / 256, 256, 0, stream>>>(out);

    long long txm = (long long)M * 64;
    k_xmean<<<(unsigned)((txm + 255) / 256), 256, 0, stream>>>((const float4*)x, out);
    k_smallmean<<<(M * 8 + 255) / 256, 256, 0, stream>>>(xpos, iat, batch, out);

    k_edges2<<<eblocks, 256, 0, stream>>>(ei, flag, out);
    k_scan512<<<1, NC, 0, stream>>>(out, S_CBN, S_CBS, S_CPS);
    k_part<<<eblocks, 512, 0, stream>>>(out);
    k_psort<<<NC, 1024, 0, stream>>>(out);
    k_scan512<<<1, NC, 0, stream>>>(out, S_UCT, S_UOF, -1);
    k_uwrite2<<<NC, 256, 0, stream>>>(out);
    k_fill<<<(unsigned)((E + 255) / 256), 256, 0, stream>>>(out);
    k_pass<<<(unsigned)((E + 255) / 256), 256, 0, stream>>>(ei, flag, out);
}